// Round 11
// baseline (332.001 us; speedup 1.0000x reference)
//
#include <hip/hip_runtime.h>
#include <math.h>

typedef unsigned long long u64;

#define W 768
#define H 768
#define NP (768*768)
#define NB 8
#define WPR 12              // u64 words per row (768/64)
#define NW (NB*H*WPR)       // total words per bit buffer = 73728
#define TH 16               // output rows per block in tiled vertical convs
#define FLOOD_PASSES 6

#define PADI(q) ((q) + ((q) >> 5))   // LDS pad: +1 word per 32

// ---------- ws layout (bytes) ----------
// 1024    : wtab floats [0..1811]:
//           [0..106] gpadH, [128..290] gpadV
//           [384+p*64]  H tables (41 entries, d=i-20, zero-padded): p:0=h0c 1=h0s 2=h1c 5=h3c
//           [768+q*128] V tables (tap at 31+j, zero-padded): q:0=v0c(R12) 1=v0s(R12) 2=v1c(R17) 5=v3c(R17)
//           [1536+ch*68] dwH edge corrections (ch: 0=(h0c,v0c) 1=(h0s,v0s) 2=(h1c,v1c) 3=(h3c,v3c))
//           [1808+ch]    TchS (H-table full sums)
// 12288   : cwv[4][768] f32 (V column weights)
// 24576   : sc (u32): [0..7] imgMinEnc [8..15] imgMaxEnc [16..23] predMinEnc
//           [24..31] predMaxEnc [32..63] fsum(f32) [64..127] chg flags
// 28672   : rsP[8][768][12] f32 enh row-sum partials (294912 B)
// 327680  : fb[4][8][6][4][768] f32 boundary f columns (2359296 B)
// 2752512 : maskBits u64[NW]
// 3407872 : seedAB u64[NW]
// 4063232 : seed13 u64[NW]
// 4718592 : reachBits u64[NW]
// 8388608 : planes: 0:b0(tmp) 1:b1(enh) 2:h0c 3:h0s 4:h1c 5:h3c

__device__ __forceinline__ unsigned fenc(float f) {
    unsigned b = __float_as_uint(f);
    return b ^ ((unsigned)((int)b >> 31) | 0x80000000u);
}
__device__ __forceinline__ float fdec(unsigned u) {
    unsigned b = (u & 0x80000000u) ? (u ^ 0x80000000u) : ~u;
    return __uint_as_float(b);
}
__device__ __forceinline__ int refl101(int i, int n) {
    if (i < 0) i = -i;
    if (i >= n) i = 2*n - 2 - i;
    return i;
}
__device__ __forceinline__ int symref(int i, int n) {
    if (i < 0) i = -1 - i;
    if (i >= n) i = 2*n - 1 - i;
    return i;
}
__device__ __forceinline__ size_t fbIdx(int g, int b, int strip, int c4, int row) {
    return ((((size_t)g*NB + b)*6 + strip)*4 + c4)*768 + row;
}

// ---------------- init: weight tables + derived weights + scalar init ----------------
__global__ void initK(float* wtab, float* cwv, unsigned* sc) {
    int t = threadIdx.x;
    double sig = 15.5, ssum = 0.0;
    for (int i = 0; i < 101; i++) { double xx = i - 50; ssum += exp(-xx*xx/(2.0*sig*sig)); }
    for (int i = t; i < 107; i += 256) {
        float v = 0.f; int j = i - 3;
        if (j >= 0 && j < 101) { double xx = j - 50; v = (float)(exp(-xx*xx/(2.0*sig*sig))/ssum); }
        wtab[i] = v;
    }
    for (int i = t; i < 163; i += 256) {
        float v = 0.f; int j = i - 31;
        if (j >= 0 && j < 101) { double xx = j - 50; v = (float)(exp(-xx*xx/(2.0*sig*sig))/ssum); }
        wtab[128 + i] = v;
    }
    const double thetas[4] = {45.0, 90.0, 135.0, 180.0};
    const int    rad[4]    = {12, 17, 12, 17};
    const double sg = ((1.0/M_PI) * sqrt(log(2.0)/2.0) * 3.0) / 0.1;
    const double C  = 1.0/(2.0*M_PI*sg*sg);
    const int hG[6]   = {0, 0, 1, 2, 2, 3};
    const int hSin[6] = {0, 1, 0, 0, 1, 0};
    for (int idx = t; idx < 6*64; idx += 256) {
        int p = idx / 64, i = idx % 64;
        int g = hG[p], r = rad[g];
        double th = thetas[g] * (M_PI / 180.0);
        double a  = 2.0*M_PI*0.1*cos(th);
        float v = 0.f;
        int d = i - 20;
        if (i < 41 && d >= -r && d <= r) {
            double dd = (double)d, G = exp(-0.5*dd*dd/(sg*sg));
            v = hSin[p] ? (float)(C*G*sin(a*dd)) : (float)(C*G*cos(a*dd));
        }
        wtab[384 + p*64 + i] = v;
    }
    const int vG[6]   = {0, 0, 1, 2, 2, 3};
    const int vSin[6] = {0, 1, 0, 0, 1, 0};
    for (int idx = t; idx < 6*128; idx += 256) {
        int q = idx / 128, i = idx % 128;
        int g = vG[q], r = rad[g];
        double th = thetas[g] * (M_PI / 180.0);
        double bb = 2.0*M_PI*0.1*sin(th);
        float v = 0.f;
        int j = i - 31;
        if (j >= 0 && j <= 2*r) {
            double dd = (double)(j - r), G = exp(-0.5*dd*dd/(sg*sg));
            v = vSin[q] ? (float)(G*sin(bb*dd)) : (float)(G*cos(bb*dd));
        }
        wtab[768 + q*128 + i] = v;
    }
    if (t < 8)  { sc[t] = 0xFFFFFFFFu; sc[8+t] = 0u; sc[16+t] = 0xFFFFFFFFu; sc[24+t] = 0u; }
    if (t >= 32 && t < 64) ((float*)sc)[t] = 0.f;        // fsum
    if (t >= 64 && t < 128) sc[t] = 0u;                  // chg flags
    __syncthreads();
    // ---- derived weights (channels: 0=(h0c,v0c) 1=(h0s,v0s) 2=(h1c,v1c) 3=(h3c,v3c)) ----
    const int hTab[4] = {0, 1, 2, 5};
    const int vTab[4] = {0, 1, 2, 5};
    const int Rv[4]   = {12, 12, 17, 17};
    if (t < 4) {
        const float* T = wtab + 384 + hTab[t]*64;
        float s = 0.f;
        for (int i = 0; i < 41; i++) s += T[i];
        wtab[1808 + t] = s;
    }
    for (int idx = t; idx < 4*68; idx += 256) {
        int ch = idx / 68, e = idx % 68;
        int c = (e < 34) ? e : 734 + (e - 34);
        const float* T = wtab + 384 + hTab[ch]*64;
        float w = 0.f;
        int lo = c - 767; if (lo < -20) lo = -20;
        int hi = c;       if (hi > 20)  hi = 20;
        for (int d = lo; d <= hi; d++) w += T[d + 20];
        if (c <= 19)  { for (int d = -20; d <= -1 - c; d++) w += T[d + 20]; }
        if (c >= 748) { for (int d = 768 - c; d <= 20; d++) w += T[d + 20]; }
        float s = 0.f;
        for (int i = 0; i < 41; i++) s += T[i];
        wtab[1536 + ch*68 + e] = w - s;
    }
    for (int idx = t; idx < 4*768; idx += 256) {
        int ch = idx / 768, r = idx % 768;
        const float* V = wtab + 768 + vTab[ch]*128;
        int off = 31 + Rv[ch];     // table idx = off + e
        float w = 0.f;
        int lo = r - 767; if (lo < -17) lo = -17;
        int hi = r;       if (hi > 17)  hi = 17;
        for (int e = lo; e <= hi; e++) w += V[off + e];
        if (r <= 16)  { for (int e = -17; e <= -1 - r; e++) w += V[off + e]; }
        if (r >= 751) { for (int e = 768 - r; e <= 17; e++) w += V[off + e]; }
        cwv[ch*768 + r] = w;
    }
}

// ---------------- per-image min/max of img and pred ----------------
__global__ void reduceK(const float* __restrict__ img, const float* __restrict__ pred,
                        unsigned* sc) {
    int b = blockIdx.y;
    int base = b*NP + blockIdx.x*9216 + threadIdx.x;
    float imn = INFINITY, imx = -INFINITY, pmn = INFINITY, pmx = -INFINITY;
    for (int k = 0; k < 36; k++) {
        float v = img[base + k*256];  imn = fminf(imn, v); imx = fmaxf(imx, v);
        float p = pred[base + k*256]; pmn = fminf(pmn, p); pmx = fmaxf(pmx, p);
    }
    for (int off = 32; off; off >>= 1) {
        imn = fminf(imn, __shfl_down(imn, off));
        imx = fmaxf(imx, __shfl_down(imx, off));
        pmn = fminf(pmn, __shfl_down(pmn, off));
        pmx = fmaxf(pmx, __shfl_down(pmx, off));
    }
    __shared__ float s[4][4];
    int lane = threadIdx.x & 63, wv = threadIdx.x >> 6;
    if (lane == 0) { s[0][wv] = imn; s[1][wv] = imx; s[2][wv] = pmn; s[3][wv] = pmx; }
    __syncthreads();
    if (threadIdx.x == 0) {
        float a0 = s[0][0], a1 = s[1][0], a2 = s[2][0], a3 = s[3][0];
        for (int w = 1; w < 4; w++) {
            a0 = fminf(a0, s[0][w]); a1 = fmaxf(a1, s[1][w]);
            a2 = fminf(a2, s[2][w]); a3 = fmaxf(a3, s[3][w]);
        }
        atomicMin(&sc[b],      fenc(a0));
        atomicMax(&sc[8 + b],  fenc(a1));
        atomicMin(&sc[16 + b], fenc(a2));
        atomicMax(&sc[24 + b], fenc(a3));
    }
}

// ---------------- Gaussian blur H: 4 outputs/thread, padded LDS ----------------
__global__ __launch_bounds__(192) void gaussHK2(const float* __restrict__ img,
                                                float* __restrict__ out,
                                                const float* __restrict__ wt,
                                                const unsigned* __restrict__ sc) {
    int b = blockIdx.y, y = blockIdx.x, t = threadIdx.x;
    float mn = fdec(sc[b]), mx = fdec(sc[8 + b]);
    float den = mx - mn;
    __shared__ float sh[896];
    const float* row = img + ((size_t)b*H + y)*W;
    for (int q = t; q < 868; q += 192) {
        int gx = refl101(q - 50, W);
        sh[PADI(q)] = (row[gx] - mn) / den;
    }
    __syncthreads();
    float a0 = 0.f, a1 = 0.f, a2 = 0.f, a3 = 0.f;
    int qb = 4*t;
    #pragma unroll
    for (int p = 0; p < 104; p++) {
        float v = sh[PADI(qb + p)];
        a0 = __fmaf_rn(wt[p + 3], v, a0);
        a1 = __fmaf_rn(wt[p + 2], v, a1);
        a2 = __fmaf_rn(wt[p + 1], v, a2);
        a3 = __fmaf_rn(wt[p    ], v, a3);
    }
    float4 o; o.x = a0; o.y = a1; o.z = a2; o.w = a3;
    *(float4*)(out + ((size_t)b*H + y)*W + qb) = o;
}

// -------- Gaussian blur V + enh + enh row-sum partials --------
__global__ __launch_bounds__(128) void gaussVK4(const float* __restrict__ tmp,
                                                const float* __restrict__ img,
                                                float* __restrict__ enh,
                                                const float* __restrict__ wt,
                                                const unsigned* __restrict__ sc,
                                                float* __restrict__ rsP) {
    int bid = blockIdx.x;
    int b = bid & 7; int r_ = bid >> 3; int tile = r_ % 48; int strip = r_ / 48;
    int y0 = tile*TH, x = strip*128 + threadIdx.x;
    float acc[TH];
    #pragma unroll
    for (int k = 0; k < TH; k++) acc[k] = 0.f;
    const float* T = tmp + (size_t)b*NP;
    for (int base = 0; base < 116; base += 4) {
        int g0 = refl101(y0+base-50, H), g1 = refl101(y0+base-49, H),
            g2 = refl101(y0+base-48, H), g3 = refl101(y0+base-47, H);
        float v0 = T[g0*W+x], v1 = T[g1*W+x], v2 = T[g2*W+x], v3 = T[g3*W+x];
        #pragma unroll
        for (int k = 0; k < TH; k++) {
            float a = acc[k];
            a = __fmaf_rn(wt[base   -k+31], v0, a);
            a = __fmaf_rn(wt[base+1 -k+31], v1, a);
            a = __fmaf_rn(wt[base+2 -k+31], v2, a);
            a = __fmaf_rn(wt[base+3 -k+31], v3, a);
            acc[k] = a;
        }
    }
    float mn = fdec(sc[b]), mx = fdec(sc[8 + b]);
    float den = mx - mn;
    int g64 = strip*2 + (threadIdx.x >> 6);
    bool l0 = (threadIdx.x & 63) == 0;
    #pragma unroll
    for (int k = 0; k < TH; k++) {
        size_t o = ((size_t)b*H + y0 + k)*W + x;
        float vv = (img[o] - mn) / den;
        float e = vv - acc[k];
        e = fminf(fmaxf(e, 0.f), 1.f);
        enh[o] = e;
        float s = e;
        for (int off = 32; off; off >>= 1) s += __shfl_down(s, off);
        if (l0) rsP[((size_t)b*H + y0 + k)*12 + g64] = s;
    }
}

// ---------------- analytic per-image fsum for 4 angles ----------------
__global__ __launch_bounds__(256) void meanK(const float* __restrict__ rsP,
        const float* __restrict__ enh, const float* __restrict__ wtab,
        const float* __restrict__ cwv, float* __restrict__ fsum) {
    int b = blockIdx.x, t = threadIdx.x;
    float S[4] = {0.f, 0.f, 0.f, 0.f};
    for (int rr = 0; rr < 3; rr++) {
        int r = t + rr*256;
        const float* P = rsP + ((size_t)b*H + r)*12;
        float rs = 0.f;
        for (int j = 0; j < 12; j++) rs += P[j];
        const float* E = enh + (size_t)b*NP + (size_t)r*W;
        #pragma unroll
        for (int ch = 0; ch < 4; ch++) {
            float RS = wtab[1808 + ch] * rs;
            const float* dw = wtab + 1536 + ch*68;
            for (int e = 0; e < 34; e++)  RS = __fmaf_rn(dw[e], E[e], RS);
            for (int e = 34; e < 68; e++) RS = __fmaf_rn(dw[e], E[700 + e], RS);
            S[ch] = __fmaf_rn(cwv[ch*768 + r], RS, S[ch]);
        }
    }
    __shared__ float sm[256];
    __shared__ float chres[4];
    for (int ch = 0; ch < 4; ch++) {
        sm[t] = S[ch]; __syncthreads();
        for (int off = 128; off; off >>= 1) {
            if (t < off) sm[t] += sm[t + off];
            __syncthreads();
        }
        if (t == 0) chres[ch] = sm[0];
        __syncthreads();
    }
    if (t == 0) {
        fsum[0*8 + b] = chres[0] - chres[1];
        fsum[1*8 + b] = chres[2];
        fsum[2*8 + b] = chres[0] + chres[1];
        fsum[3*8 + b] = chres[3];
    }
}

// ---------------- fused Gabor H: 4 planes ----------------
__global__ __launch_bounds__(192) void gaborHF4(const float* __restrict__ enh,
        float* __restrict__ h0c, float* __restrict__ h0s,
        float* __restrict__ h1c, float* __restrict__ h3c,
        const float* __restrict__ wt) {
    int b = blockIdx.y, y = blockIdx.x, t = threadIdx.x;
    __shared__ float sh[832];
    const float* row = enh + ((size_t)b*H + y)*W;
    for (int q = t; q < 802; q += 192) {
        int gx = symref(q - 17, W);
        sh[PADI(q)] = row[gx];
    }
    __syncthreads();
    const float* T0c = wt + 384; const float* T0s = wt + 448;
    const float* T1c = wt + 512; const float* T3c = wt + 704;
    float a0c[4] = {0,0,0,0}, a0s[4] = {0,0,0,0};
    float a1c[4] = {0,0,0,0}, a3c[4] = {0,0,0,0};
    int qb = 4*t;
    #pragma unroll
    for (int p = 0; p < 38; p++) {
        float v = sh[PADI(qb + p)];
        #pragma unroll
        for (int sub = 0; sub < 4; sub++) {
            int idx = p + 3 - sub;
            a0c[sub] = __fmaf_rn(T0c[idx], v, a0c[sub]);
            a0s[sub] = __fmaf_rn(T0s[idx], v, a0s[sub]);
            a1c[sub] = __fmaf_rn(T1c[idx], v, a1c[sub]);
            a3c[sub] = __fmaf_rn(T3c[idx], v, a3c[sub]);
        }
    }
    size_t o = ((size_t)b*H + y)*W + qb;
    *(float4*)(h0c + o) = make_float4(a0c[0], a0c[1], a0c[2], a0c[3]);
    *(float4*)(h0s + o) = make_float4(a0s[0], a0s[1], a0s[2], a0s[3]);
    *(float4*)(h1c + o) = make_float4(a1c[0], a1c[1], a1c[2], a1c[3]);
    *(float4*)(h3c + o) = make_float4(a3c[0], a3c[1], a3c[2], a3c[3]);
}

// ------- Gabor V 45/135 pair, fused seed: A=Vc*hc, B=Vs*hs; f0=A-B, f2=A+B -------
__global__ __launch_bounds__(128) void gaborVAB2(
        const float* __restrict__ hc, const float* __restrict__ hs,
        const float* __restrict__ Tc, const float* __restrict__ Ts,
        const float* __restrict__ fsum, u64* __restrict__ seedAB,
        float* __restrict__ fb) {
    int bid = blockIdx.x;
    int b = bid & 7; int r_ = bid >> 3; int tile = r_ % 48; int strip = r_ / 48;
    int y0 = tile*TH, x = strip*128 + threadIdx.x;
    float A[18], B[18];
    #pragma unroll
    for (int k = 0; k < 18; k++) { A[k] = 0.f; B[k] = 0.f; }
    const size_t pb = (size_t)b*NP;
    for (int bb = 0; bb < 52; bb += 2) {
        int gA = symref(y0 + bb - 18, H), gB = symref(y0 + bb - 17, H);
        size_t oA = pb + (size_t)gA*W + x, oB = pb + (size_t)gB*W + x;
        float vcA = hc[oA], vsA = hs[oA];
        float vcB = hc[oB], vsB = hs[oB];
        #pragma unroll
        for (int kk = 0; kk < 18; kk++) {
            int i26 = bb - kk + 26;
            float t = A[kk];
            t = __fmaf_rn(Tc[i26],   vcA, t);
            t = __fmaf_rn(Tc[i26+1], vcB, t);
            A[kk] = t;
            t = B[kk];
            t = __fmaf_rn(Ts[i26],   vsA, t);
            t = __fmaf_rn(Ts[i26+1], vsB, t);
            B[kk] = t;
        }
    }
    // clamp halo rows at image edges (maxfilt symmetric pad == clamp by 1)
    if (tile == 0)  { A[0] = A[1];   B[0] = B[1]; }
    if (tile == 47) { A[17] = A[16]; B[17] = B[16]; }

    int lane = threadIdx.x & 63, wv = threadIdx.x >> 6;
    bool edgeLane = (wv == 0 && lane == 0) || (wv == 1 && lane == 63);
    float mean0 = fsum[0*8 + b] / 589824.f;
    float mean2 = fsum[2*8 + b] / 589824.f;
    __shared__ float vmEdge[2][16];
    unsigned cond = 0;
    // ---- angle 0 (f0 = A - B) ----
    {
        float vm[16], c[16];
        float fm = A[0] - B[0], f0 = A[1] - B[1];
        #pragma unroll
        for (int k = 0; k < 16; k++) {
            float fp = A[k+2] - B[k+2];
            vm[k] = fmaxf(fmaxf(fm, f0), fp);
            c[k] = f0;
            fm = f0; f0 = fp;
        }
        if (wv == 0 && lane == 63) {
            #pragma unroll
            for (int k = 0; k < 16; k++) vmEdge[0][k] = vm[k];
        }
        if (wv == 1 && lane == 0)  {
            #pragma unroll
            for (int k = 0; k < 16; k++) vmEdge[1][k] = vm[k];
        }
        __syncthreads();
        #pragma unroll
        for (int k = 0; k < 16; k++) {
            float vl = __shfl_up(vm[k], 1);
            float vr = __shfl_down(vm[k], 1);
            if (wv == 1 && lane == 0)  vl = vmEdge[0][k];
            if (wv == 0 && lane == 63) vr = vmEdge[1][k];
            float mx = fmaxf(fmaxf(vl, vm[k]), vr);
            if ((c[k] == mx) && (c[k] > mean0) && !edgeLane) cond |= 1u << k;
        }
        __syncthreads();
    }
    // ---- angle 2 (f2 = A + B) ----
    {
        float vm[16], c[16];
        float fm = A[0] + B[0], f0 = A[1] + B[1];
        #pragma unroll
        for (int k = 0; k < 16; k++) {
            float fp = A[k+2] + B[k+2];
            vm[k] = fmaxf(fmaxf(fm, f0), fp);
            c[k] = f0;
            fm = f0; f0 = fp;
        }
        if (wv == 0 && lane == 63) {
            #pragma unroll
            for (int k = 0; k < 16; k++) vmEdge[0][k] = vm[k];
        }
        if (wv == 1 && lane == 0)  {
            #pragma unroll
            for (int k = 0; k < 16; k++) vmEdge[1][k] = vm[k];
        }
        __syncthreads();
        #pragma unroll
        for (int k = 0; k < 16; k++) {
            float vl = __shfl_up(vm[k], 1);
            float vr = __shfl_down(vm[k], 1);
            if (wv == 1 && lane == 0)  vl = vmEdge[0][k];
            if (wv == 0 && lane == 63) vr = vmEdge[1][k];
            float mx = fmaxf(fmaxf(vl, vm[k]), vr);
            if ((c[k] == mx) && (c[k] > mean2) && !edgeLane) cond |= 1u << k;
        }
    }
    // seed words
    #pragma unroll
    for (int k = 0; k < 16; k++) {
        u64 bits = __ballot((cond >> k) & 1u);
        if (lane == 0)
            seedAB[((size_t)b*H + y0 + k)*WPR + strip*2 + wv] = bits;
    }
    // boundary f columns for cleanup
    int c4 = -1;
    if (wv == 0 && lane == 0) c4 = 0;
    else if (wv == 0 && lane == 1) c4 = 1;
    else if (wv == 1 && lane == 62) c4 = 2;
    else if (wv == 1 && lane == 63) c4 = 3;
    if (c4 >= 0) {
        for (int kk = 1; kk <= 16; kk++) {
            int row = y0 + kk - 1;
            fb[fbIdx(0, b, strip, c4, row)] = A[kk] - B[kk];
            fb[fbIdx(2, b, strip, c4, row)] = A[kk] + B[kk];
        }
    }
}

// ------- Gabor V 90/180 pair, fused seed -------
__global__ __launch_bounds__(128) void gaborV13_2(
        const float* __restrict__ h1, const float* __restrict__ h3,
        const float* __restrict__ T1, const float* __restrict__ T3,
        const float* __restrict__ fsum, u64* __restrict__ seed13,
        float* __restrict__ fb) {
    int bid = blockIdx.x;
    int b = bid & 7; int r_ = bid >> 3; int tile = r_ % 48; int strip = r_ / 48;
    int y0 = tile*TH, x = strip*128 + threadIdx.x;
    float A1[18], A3[18];
    #pragma unroll
    for (int k = 0; k < 18; k++) { A1[k] = 0.f; A3[k] = 0.f; }
    const size_t pb = (size_t)b*NP;
    for (int bb = 0; bb < 52; bb += 2) {
        int gA = symref(y0 + bb - 18, H), gB = symref(y0 + bb - 17, H);
        size_t oA = pb + (size_t)gA*W + x, oB = pb + (size_t)gB*W + x;
        float v1A = h1[oA], v3A = h3[oA];
        float v1B = h1[oB], v3B = h3[oB];
        #pragma unroll
        for (int kk = 0; kk < 18; kk++) {
            int i31 = bb - kk + 31;
            float t = A1[kk];
            t = __fmaf_rn(T1[i31],   v1A, t);
            t = __fmaf_rn(T1[i31+1], v1B, t);
            A1[kk] = t;
            t = A3[kk];
            t = __fmaf_rn(T3[i31],   v3A, t);
            t = __fmaf_rn(T3[i31+1], v3B, t);
            A3[kk] = t;
        }
    }
    if (tile == 0)  { A1[0] = A1[1];   A3[0] = A3[1]; }
    if (tile == 47) { A1[17] = A1[16]; A3[17] = A3[16]; }

    int lane = threadIdx.x & 63, wv = threadIdx.x >> 6;
    bool edgeLane = (wv == 0 && lane == 0) || (wv == 1 && lane == 63);
    float mean1 = fsum[1*8 + b] / 589824.f;
    float mean3 = fsum[3*8 + b] / 589824.f;
    __shared__ float vmEdge[2][16];
    unsigned cond = 0;
    // ---- angle 1 ----
    {
        float vm[16], c[16];
        float fm = A1[0], f0 = A1[1];
        #pragma unroll
        for (int k = 0; k < 16; k++) {
            float fp = A1[k+2];
            vm[k] = fmaxf(fmaxf(fm, f0), fp);
            c[k] = f0;
            fm = f0; f0 = fp;
        }
        if (wv == 0 && lane == 63) {
            #pragma unroll
            for (int k = 0; k < 16; k++) vmEdge[0][k] = vm[k];
        }
        if (wv == 1 && lane == 0)  {
            #pragma unroll
            for (int k = 0; k < 16; k++) vmEdge[1][k] = vm[k];
        }
        __syncthreads();
        #pragma unroll
        for (int k = 0; k < 16; k++) {
            float vl = __shfl_up(vm[k], 1);
            float vr = __shfl_down(vm[k], 1);
            if (wv == 1 && lane == 0)  vl = vmEdge[0][k];
            if (wv == 0 && lane == 63) vr = vmEdge[1][k];
            float mx = fmaxf(fmaxf(vl, vm[k]), vr);
            if ((c[k] == mx) && (c[k] > mean1) && !edgeLane) cond |= 1u << k;
        }
        __syncthreads();
    }
    // ---- angle 3 ----
    {
        float vm[16], c[16];
        float fm = A3[0], f0 = A3[1];
        #pragma unroll
        for (int k = 0; k < 16; k++) {
            float fp = A3[k+2];
            vm[k] = fmaxf(fmaxf(fm, f0), fp);
            c[k] = f0;
            fm = f0; f0 = fp;
        }
        if (wv == 0 && lane == 63) {
            #pragma unroll
            for (int k = 0; k < 16; k++) vmEdge[0][k] = vm[k];
        }
        if (wv == 1 && lane == 0)  {
            #pragma unroll
            for (int k = 0; k < 16; k++) vmEdge[1][k] = vm[k];
        }
        __syncthreads();
        #pragma unroll
        for (int k = 0; k < 16; k++) {
            float vl = __shfl_up(vm[k], 1);
            float vr = __shfl_down(vm[k], 1);
            if (wv == 1 && lane == 0)  vl = vmEdge[0][k];
            if (wv == 0 && lane == 63) vr = vmEdge[1][k];
            float mx = fmaxf(fmaxf(vl, vm[k]), vr);
            if ((c[k] == mx) && (c[k] > mean3) && !edgeLane) cond |= 1u << k;
        }
    }
    #pragma unroll
    for (int k = 0; k < 16; k++) {
        u64 bits = __ballot((cond >> k) & 1u);
        if (lane == 0)
            seed13[((size_t)b*H + y0 + k)*WPR + strip*2 + wv] = bits;
    }
    int c4 = -1;
    if (wv == 0 && lane == 0) c4 = 0;
    else if (wv == 0 && lane == 1) c4 = 1;
    else if (wv == 1 && lane == 62) c4 = 2;
    else if (wv == 1 && lane == 63) c4 = 3;
    if (c4 >= 0) {
        for (int kk = 1; kk <= 16; kk++) {
            int row = y0 + kk - 1;
            fb[fbIdx(1, b, strip, c4, row)] = A1[kk];
            fb[fbIdx(3, b, strip, c4, row)] = A3[kk];
        }
    }
}

// ---------------- cleanup: seeds for the 12 strip-boundary columns ----------------
__global__ __launch_bounds__(768) void seedEdgeK(const float* __restrict__ fb,
        const float* __restrict__ fsum, u64* __restrict__ seedAB) {
    int b = blockIdx.x, r = threadIdx.x;
    float mean[4];
    #pragma unroll
    for (int g = 0; g < 4; g++) mean[g] = fsum[g*8 + b] / 589824.f;
    int rm = r > 0 ? r - 1 : 0, rp = r < 767 ? r + 1 : 767;
    for (int s = 0; s < 6; s++) {
        for (int side = 0; side < 2; side++) {
            bool any = false;
            #pragma unroll
            for (int g = 0; g < 4; g++) {
                const float *pm1, *p0, *pp1;
                if (side == 0) {
                    pm1 = fb + fbIdx(g, b, (s == 0) ? 0 : s - 1, (s == 0) ? 0 : 3, 0);
                    p0  = fb + fbIdx(g, b, s, 0, 0);
                    pp1 = fb + fbIdx(g, b, s, 1, 0);
                } else {
                    pm1 = fb + fbIdx(g, b, s, 2, 0);
                    p0  = fb + fbIdx(g, b, s, 3, 0);
                    pp1 = fb + fbIdx(g, b, (s == 5) ? 5 : s + 1, (s == 5) ? 3 : 0, 0);
                }
                float c = p0[r];
                float mx = c;
                mx = fmaxf(mx, pm1[rm]); mx = fmaxf(mx, pm1[r]); mx = fmaxf(mx, pm1[rp]);
                mx = fmaxf(mx, p0[rm]);  mx = fmaxf(mx, p0[rp]);
                mx = fmaxf(mx, pp1[rm]); mx = fmaxf(mx, pp1[r]); mx = fmaxf(mx, pp1[rp]);
                any = any || ((c == mx) && (c > mean[g]));
            }
            if (any) {
                size_t o = ((size_t)b*H + r)*WPR + s*2 + side;
                seedAB[o] |= side ? (1ULL << 63) : 1ULL;
            }
        }
    }
}

// ---------------- Sobel grad mask (bitpacked, XCD swizzle) ----------------
__global__ void sobelK(const float* __restrict__ enh, u64* __restrict__ maskB) {
    int bid = blockIdx.x;
    int b = bid & 7; int r_ = bid >> 3;
    int y = r_ / 3; int xs = r_ - 3*y;
    int x = xs*256 + threadIdx.x;
    const float* E = enh + (size_t)b*NP;
    int ym = y > 0 ? y-1 : 1, yp = y < H-1 ? y+1 : H-2;
    int xm = x > 0 ? x-1 : 1, xp = x < W-1 ? x+1 : W-2;
    float a00 = E[ym*W + xm], a01 = E[ym*W + x], a02 = E[ym*W + xp];
    float a10 = E[y*W + xm],                     a12 = E[y*W + xp];
    float a20 = E[yp*W + xm], a21 = E[yp*W + x], a22 = E[yp*W + xp];
    float gx = __fmaf_rn(-1.f, a00, 0.f);
    gx = __fmaf_rn( 1.f, a02, gx);
    gx = __fmaf_rn(-2.f, a10, gx);
    gx = __fmaf_rn( 2.f, a12, gx);
    gx = __fmaf_rn(-1.f, a20, gx);
    gx = __fmaf_rn( 1.f, a22, gx);
    float gy = __fmaf_rn(-1.f, a00, 0.f);
    gy = __fmaf_rn(-2.f, a01, gy);
    gy = __fmaf_rn(-1.f, a02, gy);
    gy = __fmaf_rn( 1.f, a20, gy);
    gy = __fmaf_rn( 2.f, a21, gy);
    gy = __fmaf_rn( 1.f, a22, gy);
    float s = __fadd_rn(__fmul_rn(gx, gx), __fmul_rn(gy, gy));
    float grad = (float)sqrt((double)s);
    const float THR = (float)(0.0789 + 1.0*0.0774);
    bool m = grad >= THR;
    u64 bits = __ballot(m);
    if ((threadIdx.x & 63) == 0) {
        int word = xs*4 + (threadIdx.x >> 6);
        maskB[((size_t)b*H + y)*WPR + word] = bits;
    }
}

// ------- flood: thread-per-row tiles, O(1) horizontal run-fill, guarded passes -------
__global__ __launch_bounds__(256) void floodTileK(const u64* __restrict__ Mb,
        const u64* __restrict__ S1, const u64* __restrict__ S2,
        u64* __restrict__ Rb, unsigned* __restrict__ chg, int t) {
    if (t > 0 && chg[t-1] == 0) return;
    int b = blockIdx.y;
    int y0 = blockIdx.x * 256;
    int ty = threadIdx.x;
    int y = y0 + ty;
    const u64* M = Mb + (size_t)b*H*WPR;
    const u64* SA = S1 + (size_t)b*H*WPR;
    const u64* SB = S2 + (size_t)b*H*WPR;
    u64* R = Rb + (size_t)b*H*WPR;
    u64 m[12], r[12], hT[12], hB[12];
    #pragma unroll
    for (int w = 0; w < 12; w++) {
        m[w] = M[y*WPR + w];
        r[w] = (t == 0) ? (m[w] & (SA[y*WPR + w] | SB[y*WPR + w])) : R[y*WPR + w];
    }
    bool topRow = (ty == 0), botRow = (ty == 255);
    #pragma unroll
    for (int w = 0; w < 12; w++) { hT[w] = 0ULL; hB[w] = 0ULL; }
    if (topRow && y0 > 0) {
        int hy = y0 - 1;
        #pragma unroll
        for (int w = 0; w < 12; w++)
            hT[w] = (t == 0) ? (M[hy*WPR+w] & (SA[hy*WPR+w] | SB[hy*WPR+w])) : R[hy*WPR+w];
    }
    if (botRow && y0 + 256 < H) {
        int hy = y0 + 256;
        #pragma unroll
        for (int w = 0; w < 12; w++)
            hB[w] = (t == 0) ? (M[hy*WPR+w] & (SA[hy*WPR+w] | SB[hy*WPR+w])) : R[hy*WPR+w];
    }
    __shared__ u64 L[256][12];
    __shared__ unsigned chgArr[4];
    #pragma unroll
    for (int w = 0; w < 12; w++) L[ty][w] = r[w];
    __syncthreads();
    int wvid = ty >> 6, lane = ty & 63;
    bool grew = false;
    while (true) {
        u64 D[12], F[12];
        #pragma unroll
        for (int w = 0; w < 12; w++) {
            u64 up = topRow ? hT[w] : L[ty-1][w];
            u64 dn = botRow ? hB[w] : L[ty+1][w];
            D[w] = r[w] | up | dn;
        }
        #pragma unroll
        for (int w = 0; w < 12; w++) {
            u64 s = D[w] | (D[w] << 1) | (D[w] >> 1);
            if (w > 0)  s |= D[w-1] >> 63;
            if (w < 11) s |= D[w+1] << 63;
            F[w] = s & m[w];
        }
        {
            u64 c = 0;
            #pragma unroll
            for (int w = 0; w < 12; w++) {
                u64 sd = (F[w] | c) & m[w];
                u64 uf = m[w] & ~(m[w] + sd);
                F[w] = uf | sd;
                c = uf >> 63;
            }
        }
        {
            u64 c = 0;
            #pragma unroll
            for (int w = 11; w >= 0; w--) {
                u64 sd = (F[w] | (c << 63)) & m[w];
                u64 bm = __brevll(m[w]);
                u64 df = __brevll(bm & ~(bm + __brevll(sd)));
                F[w] = df | sd;
                c = df & 1ULL;
            }
        }
        bool chgT = false;
        #pragma unroll
        for (int w = 0; w < 12; w++) if (F[w] != r[w]) chgT = true;
        bool wc = __any(chgT);
        if (lane == 0) chgArr[wvid] = wc ? 1u : 0u;
        __syncthreads();
        #pragma unroll
        for (int w = 0; w < 12; w++) { r[w] = F[w]; L[ty][w] = F[w]; }
        unsigned any = chgArr[0] | chgArr[1] | chgArr[2] | chgArr[3];
        __syncthreads();
        if (!any) break;
        grew = true;
    }
    #pragma unroll
    for (int w = 0; w < 12; w++) R[y*WPR + w] = r[w];
    if (grew && ty == 0) atomicOr(&chg[t], 1u);
}

// ---------------- final: out = (sigmoid?(pred)>0.5) | reach ----------------
__global__ void finalK(const float* __restrict__ pred, const u64* __restrict__ reachB,
                       const unsigned* __restrict__ sc, float* __restrict__ out) {
    int b = blockIdx.z, y = blockIdx.y, x = blockIdx.x*256 + threadIdx.x;
    float pmn = fdec(sc[16 + b]), pmx = fdec(sc[24 + b]);
    bool needSig = (pmx > 1.0f) || (pmn < 0.0f);
    float p = pred[((size_t)b*H + y)*W + x];
    float pv;
    if (needSig) {
        float e = (float)exp(-(double)p);
        pv = 1.f / (1.f + e);
    } else {
        pv = p;
    }
    bool on = pv > 0.5f;
    u64 w = reachB[((size_t)b*H + y)*WPR + (x >> 6)];
    on = on || ((w >> (x & 63)) & 1ULL);
    out[((size_t)b*H + y)*W + x] = on ? 1.f : 0.f;
}

extern "C" void kernel_launch(void* const* d_in, const int* in_sizes, int n_in,
                              void* d_out, int out_size, void* d_ws, size_t ws_size,
                              hipStream_t stream) {
    const float* pred = (const float*)d_in[0];
    const float* img  = (const float*)d_in[1];
    float* out = (float*)d_out;
    char* ws = (char*)d_ws;

    float*    wtab   = (float*)(ws + 1024);
    float*    cwv    = (float*)(ws + 12288);
    unsigned* sc     = (unsigned*)(ws + 24576);
    float*    fsum   = ((float*)sc) + 32;
    unsigned* chg    = sc + 64;
    float*    rsP    = (float*)(ws + 28672);
    float*    fb     = (float*)(ws + 327680);
    u64*      maskB  = (u64*)(ws + 2752512);
    u64*      seedAB = (u64*)(ws + 3407872);
    u64*      seed13 = (u64*)(ws + 4063232);
    u64*      reachB = (u64*)(ws + 4718592);
    const size_t PL = (size_t)NB*NP;
    float* plane = (float*)(ws + 8388608);
    float* b0  = plane;          // gauss tmp
    float* b1  = plane + PL;     // enh
    float* h0c = plane + 2*PL; float* h0s = plane + 3*PL;
    float* h1c = plane + 4*PL; float* h3c = plane + 5*PL;

    const float* gpadH = wtab;
    const float* gpadV = wtab + 128;

    initK<<<1, 256, 0, stream>>>(wtab, cwv, sc);
    reduceK<<<dim3(64, 8), 256, 0, stream>>>(img, pred, sc);

    dim3 gRow(768, 8);
    gaussHK2<<<gRow, 192, 0, stream>>>(img, b0, gpadH, sc);
    gaussVK4<<<2304, 128, 0, stream>>>(b0, img, b1, gpadV, sc, rsP);

    meanK<<<8, 256, 0, stream>>>(rsP, b1, wtab, cwv, fsum);
    sobelK<<<18432, 256, 0, stream>>>(b1, maskB);

    gaborHF4<<<gRow, 192, 0, stream>>>(b1, h0c, h0s, h1c, h3c, wtab);

    gaborVAB2<<<2304, 128, 0, stream>>>(h0c, h0s, wtab + 768, wtab + 896,
                                        fsum, seedAB, fb);
    gaborV13_2<<<2304, 128, 0, stream>>>(h1c, h3c, wtab + 1024, wtab + 1408,
                                         fsum, seed13, fb);
    seedEdgeK<<<8, 768, 0, stream>>>(fb, fsum, seedAB);

    for (int t = 0; t < FLOOD_PASSES; t++)
        floodTileK<<<dim3(3, 8), 256, 0, stream>>>(maskB, seedAB, seed13, reachB, chg, t);

    finalK<<<dim3(3, H, 8), 256, 0, stream>>>(pred, reachB, sc, out);
}

// Round 12
// 248.125 us; speedup vs baseline: 1.3380x; 1.3380x over previous
//
#include <hip/hip_runtime.h>
#include <math.h>

typedef unsigned long long u64;

#define W 768
#define H 768
#define NP (768*768)
#define NB 8
#define WPR 12              // u64 words per row (768/64)
#define NW (NB*H*WPR)       // total words per bit buffer = 73728
#define TH 16               // output rows per block in tiled vertical convs
#define P12N 73728          // floats per p12 angle region (8*768*12)
#define FLOOD_PASSES 6

#define PADI(q) ((q) + ((q) >> 5))   // LDS pad: +1 word per 32

// ---------- ws layout (bytes) ----------
// 1024    : wtab (floats, 1536 entries):
//           [0..106] gpadH, [128..290] gpadV
//           [384+p*64]  H tables (41 real entries at [3..43]): p:0=h0c 1=h0s 2=h1c 5=h3c
//           [768+q*128] V tables (tap j at [31+j], zero-padded):
//                q: 0=v0c(R12) 1=v0s(R12) 2=v1c(R17) 5=v3c(R17)
// 16384   : sc (u32): [0..7] imgMinEnc [8..15] imgMaxEnc [16..23] predMinEnc
//           [24..31] predMaxEnc [32..63] fsum(f32) [64..127] chg flags
// 20480   : p12[4 angles][73728] f32
// 1310720 : maskBits u64[NW]
// 1900544 : seedBits u64[NW]
// 2490368 : reachBits u64[NW]
// 4 MiB   : planes: 0:b0(tmp) 1:b1(enh) 2:h0c 3:h0s 4:h1c 5:h3c 8:f0 9:f1 10:f2 11:f3

__device__ __forceinline__ unsigned fenc(float f) {
    unsigned b = __float_as_uint(f);
    return b ^ ((unsigned)((int)b >> 31) | 0x80000000u);
}
__device__ __forceinline__ float fdec(unsigned u) {
    unsigned b = (u & 0x80000000u) ? (u ^ 0x80000000u) : ~u;
    return __uint_as_float(b);
}
__device__ __forceinline__ int refl101(int i, int n) {
    if (i < 0) i = -i;
    if (i >= n) i = 2*n - 2 - i;
    return i;
}
__device__ __forceinline__ int symref(int i, int n) {
    if (i < 0) i = -1 - i;
    if (i >= n) i = 2*n - 1 - i;
    return i;
}

// ---------------- init: parallel weight tables + scalar init ----------------
__global__ void initK(float* wtab, unsigned* sc) {
    int t = threadIdx.x;
    __shared__ double gd[101];
    __shared__ double ssumS;
    const double sig = 15.5;
    if (t < 101) { double xx = t - 50; gd[t] = exp(-xx*xx/(2.0*sig*sig)); }
    __syncthreads();
    if (t == 0) {
        double s = 0.0;                       // identical sequential order -> identical ssum
        for (int i = 0; i < 101; i++) s += gd[i];
        ssumS = s;
    }
    __syncthreads();
    double ssum = ssumS;
    for (int i = t; i < 107; i += 256) {      // gpadH: tap j at [3+j]
        float v = 0.f; int j = i - 3;
        if (j >= 0 && j < 101) v = (float)(gd[j]/ssum);
        wtab[i] = v;
    }
    for (int i = t; i < 163; i += 256) {      // gpadV: tap j at [31+j]
        float v = 0.f; int j = i - 31;
        if (j >= 0 && j < 101) v = (float)(gd[j]/ssum);
        wtab[128 + i] = v;
    }
    const double thetas[4] = {45.0, 90.0, 135.0, 180.0};
    const int    rad[4]    = {12, 17, 12, 17};
    const double sg = ((1.0/M_PI) * sqrt(log(2.0)/2.0) * 3.0) / 0.1;
    const double C  = 1.0/(2.0*M_PI*sg*sg);
    const int hG[6]   = {0, 0, 1, 2, 2, 3};
    const int hSin[6] = {0, 1, 0, 0, 1, 0};
    for (int idx = t; idx < 6*64; idx += 256) {
        int p = idx / 64, i = idx % 64;
        int g = hG[p], r = rad[g];
        double th = thetas[g] * (M_PI / 180.0);
        double a  = 2.0*M_PI*0.1*cos(th);
        float v = 0.f;
        int d = i - 20;
        if (i < 41 && d >= -r && d <= r) {
            double dd = (double)d, G = exp(-0.5*dd*dd/(sg*sg));
            v = hSin[p] ? (float)(C*G*sin(a*dd)) : (float)(C*G*cos(a*dd));
        }
        wtab[384 + p*64 + i] = v;
    }
    const int vG[6]   = {0, 0, 1, 2, 2, 3};
    const int vSin[6] = {0, 1, 0, 0, 1, 0};
    for (int idx = t; idx < 6*128; idx += 256) {
        int q = idx / 128, i = idx % 128;
        int g = vG[q], r = rad[g];
        double th = thetas[g] * (M_PI / 180.0);
        double bb = 2.0*M_PI*0.1*sin(th);
        float v = 0.f;
        int j = i - 31;
        if (j >= 0 && j <= 2*r) {
            double dd = (double)(j - r), G = exp(-0.5*dd*dd/(sg*sg));
            v = vSin[q] ? (float)(G*sin(bb*dd)) : (float)(G*cos(bb*dd));
        }
        wtab[768 + q*128 + i] = v;
    }
    if (t < 8)  { sc[t] = 0xFFFFFFFFu; sc[8+t] = 0u; sc[16+t] = 0xFFFFFFFFu; sc[24+t] = 0u; }
    if (t >= 32 && t < 64) ((float*)sc)[t] = 0.f;        // fsum
    if (t >= 64 && t < 128) sc[t] = 0u;                  // chg flags
}

// ---------------- per-image min/max of img and pred ----------------
__global__ void reduceK(const float* __restrict__ img, const float* __restrict__ pred,
                        unsigned* sc) {
    int b = blockIdx.y;
    int base = b*NP + blockIdx.x*9216 + threadIdx.x;
    float imn = INFINITY, imx = -INFINITY, pmn = INFINITY, pmx = -INFINITY;
    for (int k = 0; k < 36; k++) {
        float v = img[base + k*256];  imn = fminf(imn, v); imx = fmaxf(imx, v);
        float p = pred[base + k*256]; pmn = fminf(pmn, p); pmx = fmaxf(pmx, p);
    }
    for (int off = 32; off; off >>= 1) {
        imn = fminf(imn, __shfl_down(imn, off));
        imx = fmaxf(imx, __shfl_down(imx, off));
        pmn = fminf(pmn, __shfl_down(pmn, off));
        pmx = fmaxf(pmx, __shfl_down(pmx, off));
    }
    __shared__ float s[4][4];
    int lane = threadIdx.x & 63, wv = threadIdx.x >> 6;
    if (lane == 0) { s[0][wv] = imn; s[1][wv] = imx; s[2][wv] = pmn; s[3][wv] = pmx; }
    __syncthreads();
    if (threadIdx.x == 0) {
        float a0 = s[0][0], a1 = s[1][0], a2 = s[2][0], a3 = s[3][0];
        for (int w = 1; w < 4; w++) {
            a0 = fminf(a0, s[0][w]); a1 = fmaxf(a1, s[1][w]);
            a2 = fminf(a2, s[2][w]); a3 = fmaxf(a3, s[3][w]);
        }
        atomicMin(&sc[b],      fenc(a0));
        atomicMax(&sc[8 + b],  fenc(a1));
        atomicMin(&sc[16 + b], fenc(a2));
        atomicMax(&sc[24 + b], fenc(a3));
    }
}

// ---------------- Gaussian blur H: 4 outputs/thread, padded LDS ----------------
__global__ __launch_bounds__(192) void gaussHK2(const float* __restrict__ img,
                                                float* __restrict__ out,
                                                const float* __restrict__ wt,
                                                const unsigned* __restrict__ sc) {
    int b = blockIdx.y, y = blockIdx.x, t = threadIdx.x;
    float mn = fdec(sc[b]), mx = fdec(sc[8 + b]);
    float den = mx - mn;
    __shared__ float sh[896];
    const float* row = img + ((size_t)b*H + y)*W;
    for (int q = t; q < 868; q += 192) {
        int gx = refl101(q - 50, W);
        sh[PADI(q)] = (row[gx] - mn) / den;
    }
    __syncthreads();
    float a0 = 0.f, a1 = 0.f, a2 = 0.f, a3 = 0.f;
    int qb = 4*t;
    #pragma unroll
    for (int p = 0; p < 104; p++) {
        float v = sh[PADI(qb + p)];
        a0 = __fmaf_rn(wt[p + 3], v, a0);
        a1 = __fmaf_rn(wt[p + 2], v, a1);
        a2 = __fmaf_rn(wt[p + 1], v, a2);
        a3 = __fmaf_rn(wt[p    ], v, a3);
    }
    float4 o; o.x = a0; o.y = a1; o.z = a2; o.w = a3;
    *(float4*)(out + ((size_t)b*H + y)*W + qb) = o;
}

// ---------------- Gaussian blur V: unroll x4, XCD-resident image ----------------
__global__ __launch_bounds__(128) void gaussVK4(const float* __restrict__ tmp,
                                                const float* __restrict__ img,
                                                float* __restrict__ enh,
                                                const float* __restrict__ wt,
                                                const unsigned* __restrict__ sc) {
    int bid = blockIdx.x;
    int b = bid & 7; int r_ = bid >> 3; int tile = r_ % 48; int strip = r_ / 48;
    int y0 = tile*TH, x = strip*128 + threadIdx.x;
    float acc[TH];
    #pragma unroll
    for (int k = 0; k < TH; k++) acc[k] = 0.f;
    const float* T = tmp + (size_t)b*NP;
    for (int base = 0; base < 116; base += 4) {
        int g0 = refl101(y0+base-50, H), g1 = refl101(y0+base-49, H),
            g2 = refl101(y0+base-48, H), g3 = refl101(y0+base-47, H);
        float v0 = T[g0*W+x], v1 = T[g1*W+x], v2 = T[g2*W+x], v3 = T[g3*W+x];
        #pragma unroll
        for (int k = 0; k < TH; k++) {
            float a = acc[k];
            a = __fmaf_rn(wt[base   -k+31], v0, a);
            a = __fmaf_rn(wt[base+1 -k+31], v1, a);
            a = __fmaf_rn(wt[base+2 -k+31], v2, a);
            a = __fmaf_rn(wt[base+3 -k+31], v3, a);
            acc[k] = a;
        }
    }
    float mn = fdec(sc[b]), mx = fdec(sc[8 + b]);
    float den = mx - mn;
    #pragma unroll
    for (int k = 0; k < TH; k++) {
        size_t o = ((size_t)b*H + y0 + k)*W + x;
        float vv = (img[o] - mn) / den;
        float e = vv - acc[k];
        e = fminf(fmaxf(e, 0.f), 1.f);
        enh[o] = e;
    }
}

// ---------------- fused Gabor H: 4 planes (h2c==h0c, h2s==-h0s dropped) ----------------
__global__ __launch_bounds__(192) void gaborHF4(const float* __restrict__ enh,
        float* __restrict__ h0c, float* __restrict__ h0s,
        float* __restrict__ h1c, float* __restrict__ h3c,
        const float* __restrict__ wt) {
    int b = blockIdx.y, y = blockIdx.x, t = threadIdx.x;
    __shared__ float sh[832];
    const float* row = enh + ((size_t)b*H + y)*W;
    for (int q = t; q < 802; q += 192) {
        int gx = symref(q - 17, W);
        sh[PADI(q)] = row[gx];
    }
    __syncthreads();
    const float* T0c = wt + 384; const float* T0s = wt + 448;
    const float* T1c = wt + 512; const float* T3c = wt + 704;
    float a0c[4] = {0,0,0,0}, a0s[4] = {0,0,0,0};
    float a1c[4] = {0,0,0,0}, a3c[4] = {0,0,0,0};
    int qb = 4*t;
    #pragma unroll
    for (int p = 0; p < 38; p++) {
        float v = sh[PADI(qb + p)];
        #pragma unroll
        for (int sub = 0; sub < 4; sub++) {
            int idx = p + 3 - sub;
            a0c[sub] = __fmaf_rn(T0c[idx], v, a0c[sub]);
            a0s[sub] = __fmaf_rn(T0s[idx], v, a0s[sub]);
            a1c[sub] = __fmaf_rn(T1c[idx], v, a1c[sub]);
            a3c[sub] = __fmaf_rn(T3c[idx], v, a3c[sub]);
        }
    }
    size_t o = ((size_t)b*H + y)*W + qb;
    *(float4*)(h0c + o) = make_float4(a0c[0], a0c[1], a0c[2], a0c[3]);
    *(float4*)(h0s + o) = make_float4(a0s[0], a0s[1], a0s[2], a0s[3]);
    *(float4*)(h1c + o) = make_float4(a1c[0], a1c[1], a1c[2], a1c[3]);
    *(float4*)(h3c + o) = make_float4(a3c[0], a3c[1], a3c[2], a3c[3]);
}

// ------- Gabor V, 45/135 pair: A=Vc*hc, B=Vs*hs -> f0=A-B, f2=A+B -------
__global__ __launch_bounds__(128) void gaborVAB(
        const float* __restrict__ hc, const float* __restrict__ hs,
        float* __restrict__ f0, float* __restrict__ f2,
        const float* __restrict__ Tc, const float* __restrict__ Ts,
        float* __restrict__ p0, float* __restrict__ p2) {
    int bid = blockIdx.x;
    int b = bid & 7; int r_ = bid >> 3; int tile = r_ % 48; int strip = r_ / 48;
    int y0 = tile*TH, x = strip*128 + threadIdx.x;
    float A[TH], Bm[TH];
    #pragma unroll
    for (int k = 0; k < TH; k++) { A[k] = 0.f; Bm[k] = 0.f; }
    const size_t pb = (size_t)b*NP;
    for (int base = 0; base < 50; base += 2) {
        int gA = symref(y0 + base - 17, H), gB = symref(y0 + base - 16, H);
        size_t oA = pb + (size_t)gA*W + x, oB = pb + (size_t)gB*W + x;
        float vcA = hc[oA], vsA = hs[oA];
        float vcB = hc[oB], vsB = hs[oB];
        #pragma unroll
        for (int k = 0; k < TH; k++) {
            int i26 = base - k + 26;
            float t = A[k];
            t = __fmaf_rn(Tc[i26],   vcA, t);
            t = __fmaf_rn(Tc[i26+1], vcB, t);
            A[k] = t;
            t = Bm[k];
            t = __fmaf_rn(Ts[i26],   vsA, t);
            t = __fmaf_rn(Ts[i26+1], vsB, t);
            Bm[k] = t;
        }
    }
    int g64 = strip*2 + (threadIdx.x >> 6);
    bool l0 = (threadIdx.x & 63) == 0;
    #pragma unroll
    for (int k = 0; k < TH; k++) {
        size_t o = ((size_t)b*H + y0 + k)*W + x;
        size_t po = ((size_t)b*H + y0 + k)*12 + g64;
        float v0 = A[k] - Bm[k];
        float v2 = A[k] + Bm[k];
        f0[o] = v0;
        float s = v0;
        for (int off = 32; off; off >>= 1) s += __shfl_down(s, off);
        if (l0) p0[po] = s;
        f2[o] = v2;
        s = v2;
        for (int off = 32; off; off >>= 1) s += __shfl_down(s, off);
        if (l0) p2[po] = s;
    }
}

// ------- Gabor V, 90/180 pair: two independent 1-plane chains -------
__global__ __launch_bounds__(128) void gaborV13(
        const float* __restrict__ h1, const float* __restrict__ h3,
        float* __restrict__ f1, float* __restrict__ f3,
        const float* __restrict__ T1, const float* __restrict__ T3,
        float* __restrict__ p1, float* __restrict__ p3) {
    int bid = blockIdx.x;
    int b = bid & 7; int r_ = bid >> 3; int tile = r_ % 48; int strip = r_ / 48;
    int y0 = tile*TH, x = strip*128 + threadIdx.x;
    float a1[TH], a3[TH];
    #pragma unroll
    for (int k = 0; k < TH; k++) { a1[k] = 0.f; a3[k] = 0.f; }
    const size_t pb = (size_t)b*NP;
    for (int base = 0; base < 50; base += 2) {
        int gA = symref(y0 + base - 17, H), gB = symref(y0 + base - 16, H);
        size_t oA = pb + (size_t)gA*W + x, oB = pb + (size_t)gB*W + x;
        float v1A = h1[oA], v3A = h3[oA];
        float v1B = h1[oB], v3B = h3[oB];
        #pragma unroll
        for (int k = 0; k < TH; k++) {
            int i31 = base - k + 31;
            float t = a1[k];
            t = __fmaf_rn(T1[i31],   v1A, t);
            t = __fmaf_rn(T1[i31+1], v1B, t);
            a1[k] = t;
            t = a3[k];
            t = __fmaf_rn(T3[i31],   v3A, t);
            t = __fmaf_rn(T3[i31+1], v3B, t);
            a3[k] = t;
        }
    }
    int g64 = strip*2 + (threadIdx.x >> 6);
    bool l0 = (threadIdx.x & 63) == 0;
    #pragma unroll
    for (int k = 0; k < TH; k++) {
        size_t o = ((size_t)b*H + y0 + k)*W + x;
        size_t po = ((size_t)b*H + y0 + k)*12 + g64;
        f1[o] = a1[k];
        float s = a1[k];
        for (int off = 32; off; off >>= 1) s += __shfl_down(s, off);
        if (l0) p1[po] = s;
        f3[o] = a3[k];
        s = a3[k];
        for (int off = 32; off; off >>= 1) s += __shfl_down(s, off);
        if (l0) p3[po] = s;
    }
}

// ---------------- deterministic per-image sums, all 4 angles ----------------
__global__ void sumKAll(const float* __restrict__ p12, float* fsum) {
    int b = blockIdx.x, g = blockIdx.y, t = threadIdx.x;
    const float* P = p12 + (size_t)g*P12N;
    float s = 0.f;
    for (int k = 0; k < 9; k++) {
        int idx = t + k*256;                 // 0..2303 == row*3 + strip
        int row = idx / 3, strip = idx - row*3;
        const float* Q = P + ((size_t)b*H + row)*12 + strip*4;
        float p4 = ((Q[0] + Q[1]) + Q[2]) + Q[3];
        s += p4;
    }
    __shared__ float sm[256];
    sm[t] = s; __syncthreads();
    for (int off = 128; off; off >>= 1) {
        if (t < off) sm[t] += sm[t + off];
        __syncthreads();
    }
    if (t == 0) fsum[g*8 + b] = sm[0];
}

// ---------------- seeds: row-tiled, 4 planes sequential in LDS (XCD swizzle) ----------------
__global__ __launch_bounds__(256) void seedK4(const float* __restrict__ f0,
        const float* __restrict__ f1, const float* __restrict__ f2,
        const float* __restrict__ f3, const float* __restrict__ fsum,
        u64* __restrict__ seedB) {
    int bid = blockIdx.x;
    int b = bid & 7; int r_ = bid >> 3;          // 0..143
    int y0 = (r_ % 48)*16; int xb = r_ / 48;     // 0..2
    int x0 = xb*256, t = threadIdx.x;
    __shared__ float sh[18][258];
    const float* planes[4] = {f0, f1, f2, f3};
    unsigned condMask = 0;
    #pragma unroll
    for (int a = 0; a < 4; a++) {
        const float* F = planes[a] + (size_t)b*NP;
        __syncthreads();
        for (int idx = t; idx < 18*258; idx += 256) {
            int rr = idx / 258, q = idx - rr*258;
            int gy = y0 - 1 + rr; gy = gy < 0 ? 0 : (gy > H-1 ? H-1 : gy);
            int gx = x0 - 1 + q;  gx = gx < 0 ? 0 : (gx > W-1 ? W-1 : gx);
            sh[rr][q] = F[gy*W + gx];
        }
        __syncthreads();
        float mean = fsum[a*8 + b] / 589824.f;
        #pragma unroll
        for (int r = 0; r < 16; r++) {
            float c = sh[r+1][t+1];
            float mx = c;
            mx = fmaxf(mx, sh[r  ][t]); mx = fmaxf(mx, sh[r  ][t+1]); mx = fmaxf(mx, sh[r  ][t+2]);
            mx = fmaxf(mx, sh[r+1][t]); mx = fmaxf(mx, sh[r+1][t+1]); mx = fmaxf(mx, sh[r+1][t+2]);
            mx = fmaxf(mx, sh[r+2][t]); mx = fmaxf(mx, sh[r+2][t+1]); mx = fmaxf(mx, sh[r+2][t+2]);
            if ((c == mx) && (c > mean)) condMask |= (1u << r);
        }
    }
    int wv = t >> 6, lane = t & 63;
    #pragma unroll
    for (int r = 0; r < 16; r++) {
        u64 m = __ballot((condMask >> r) & 1u);
        if (lane == 0)
            seedB[((size_t)b*H + y0 + r)*WPR + xb*4 + wv] = m;
    }
}

// ---------------- Sobel grad mask (bitpacked, XCD swizzle) ----------------
__global__ void sobelK(const float* __restrict__ enh, u64* __restrict__ maskB) {
    int bid = blockIdx.x;
    int b = bid & 7; int r_ = bid >> 3;     // 0..2303
    int y = r_ / 3; int xs = r_ - 3*y;
    int x = xs*256 + threadIdx.x;
    const float* E = enh + (size_t)b*NP;
    int ym = y > 0 ? y-1 : 1, yp = y < H-1 ? y+1 : H-2;   // reflect101
    int xm = x > 0 ? x-1 : 1, xp = x < W-1 ? x+1 : W-2;
    float a00 = E[ym*W + xm], a01 = E[ym*W + x], a02 = E[ym*W + xp];
    float a10 = E[y*W + xm],                     a12 = E[y*W + xp];
    float a20 = E[yp*W + xm], a21 = E[yp*W + x], a22 = E[yp*W + xp];
    float gx = __fmaf_rn(-1.f, a00, 0.f);
    gx = __fmaf_rn( 1.f, a02, gx);
    gx = __fmaf_rn(-2.f, a10, gx);
    gx = __fmaf_rn( 2.f, a12, gx);
    gx = __fmaf_rn(-1.f, a20, gx);
    gx = __fmaf_rn( 1.f, a22, gx);
    float gy = __fmaf_rn(-1.f, a00, 0.f);
    gy = __fmaf_rn(-2.f, a01, gy);
    gy = __fmaf_rn(-1.f, a02, gy);
    gy = __fmaf_rn( 1.f, a20, gy);
    gy = __fmaf_rn( 2.f, a21, gy);
    gy = __fmaf_rn( 1.f, a22, gy);
    float s = __fadd_rn(__fmul_rn(gx, gx), __fmul_rn(gy, gy));
    float grad = (float)sqrt((double)s);
    const float THR = (float)(0.0789 + 1.0*0.0774);
    bool m = grad >= THR;
    u64 bits = __ballot(m);
    if ((threadIdx.x & 63) == 0) {
        int word = xs*4 + (threadIdx.x >> 6);
        maskB[((size_t)b*H + y)*WPR + word] = bits;
    }
}

// ------- flood: thread-per-row tiles (256 rows), O(1) horizontal run-fill, guarded passes -------
__global__ __launch_bounds__(256) void floodTileK(const u64* __restrict__ Mb,
        const u64* __restrict__ seedB, u64* __restrict__ Rb,
        unsigned* __restrict__ chg, int t) {
    if (t > 0 && chg[t-1] == 0) return;
    int b = blockIdx.y;
    int y0 = blockIdx.x * 256;
    int ty = threadIdx.x;
    int y = y0 + ty;
    const u64* M = Mb + (size_t)b*H*WPR;
    const u64* S = seedB + (size_t)b*H*WPR;
    u64* R = Rb + (size_t)b*H*WPR;
    u64 m[12], r[12], hT[12], hB[12];
    #pragma unroll
    for (int w = 0; w < 12; w++) {
        m[w] = M[y*WPR + w];
        r[w] = (t == 0) ? (m[w] & S[y*WPR + w]) : R[y*WPR + w];
    }
    bool topRow = (ty == 0), botRow = (ty == 255);
    #pragma unroll
    for (int w = 0; w < 12; w++) { hT[w] = 0ULL; hB[w] = 0ULL; }
    if (topRow && y0 > 0) {
        int hy = y0 - 1;
        #pragma unroll
        for (int w = 0; w < 12; w++)
            hT[w] = (t == 0) ? (M[hy*WPR+w] & S[hy*WPR+w]) : R[hy*WPR+w];
    }
    if (botRow && y0 + 256 < H) {
        int hy = y0 + 256;
        #pragma unroll
        for (int w = 0; w < 12; w++)
            hB[w] = (t == 0) ? (M[hy*WPR+w] & S[hy*WPR+w]) : R[hy*WPR+w];
    }
    __shared__ u64 L[256][12];
    __shared__ unsigned chgArr[4];
    #pragma unroll
    for (int w = 0; w < 12; w++) L[ty][w] = r[w];
    __syncthreads();
    int wvid = ty >> 6, lane = ty & 63;
    bool grew = false;
    while (true) {
        u64 D[12], F[12];
        #pragma unroll
        for (int w = 0; w < 12; w++) {
            u64 up = topRow ? hT[w] : L[ty-1][w];
            u64 dn = botRow ? hB[w] : L[ty+1][w];
            D[w] = r[w] | up | dn;
        }
        #pragma unroll
        for (int w = 0; w < 12; w++) {
            u64 s = D[w] | (D[w] << 1) | (D[w] >> 1);
            if (w > 0)  s |= D[w-1] >> 63;
            if (w < 11) s |= D[w+1] << 63;
            F[w] = s & m[w];
        }
        {
            u64 c = 0;
            #pragma unroll
            for (int w = 0; w < 12; w++) {
                u64 sd = (F[w] | c) & m[w];
                u64 uf = m[w] & ~(m[w] + sd);
                F[w] = uf | sd;
                c = uf >> 63;
            }
        }
        {
            u64 c = 0;
            #pragma unroll
            for (int w = 11; w >= 0; w--) {
                u64 sd = (F[w] | (c << 63)) & m[w];
                u64 bm = __brevll(m[w]);
                u64 df = __brevll(bm & ~(bm + __brevll(sd)));
                F[w] = df | sd;
                c = df & 1ULL;
            }
        }
        bool chgT = false;
        #pragma unroll
        for (int w = 0; w < 12; w++) if (F[w] != r[w]) chgT = true;
        bool wc = __any(chgT);
        if (lane == 0) chgArr[wvid] = wc ? 1u : 0u;
        __syncthreads();
        #pragma unroll
        for (int w = 0; w < 12; w++) { r[w] = F[w]; L[ty][w] = F[w]; }
        unsigned any = chgArr[0] | chgArr[1] | chgArr[2] | chgArr[3];
        __syncthreads();
        if (!any) break;
        grew = true;
    }
    #pragma unroll
    for (int w = 0; w < 12; w++) R[y*WPR + w] = r[w];
    if (grew && ty == 0) atomicOr(&chg[t], 1u);
}

// ---------------- final: out = (sigmoid?(pred)>0.5) | reach ----------------
__global__ void finalK(const float* __restrict__ pred, const u64* __restrict__ reachB,
                       const unsigned* __restrict__ sc, float* __restrict__ out) {
    int b = blockIdx.z, y = blockIdx.y, x = blockIdx.x*256 + threadIdx.x;
    float pmn = fdec(sc[16 + b]), pmx = fdec(sc[24 + b]);
    bool needSig = (pmx > 1.0f) || (pmn < 0.0f);
    float p = pred[((size_t)b*H + y)*W + x];
    float pv;
    if (needSig) {
        float e = (float)exp(-(double)p);
        pv = 1.f / (1.f + e);
    } else {
        pv = p;
    }
    bool on = pv > 0.5f;
    u64 w = reachB[((size_t)b*H + y)*WPR + (x >> 6)];
    on = on || ((w >> (x & 63)) & 1ULL);
    out[((size_t)b*H + y)*W + x] = on ? 1.f : 0.f;
}

extern "C" void kernel_launch(void* const* d_in, const int* in_sizes, int n_in,
                              void* d_out, int out_size, void* d_ws, size_t ws_size,
                              hipStream_t stream) {
    const float* pred = (const float*)d_in[0];
    const float* img  = (const float*)d_in[1];
    float* out = (float*)d_out;
    char* ws = (char*)d_ws;

    float*    wtab   = (float*)(ws + 1024);
    unsigned* sc     = (unsigned*)(ws + 16384);
    float*    fsum   = ((float*)sc) + 32;
    unsigned* chg    = sc + 64;
    float*    p12    = (float*)(ws + 20480);
    u64*      maskB  = (u64*)(ws + 1310720);
    u64*      seedB  = (u64*)(ws + 1900544);
    u64*      reachB = (u64*)(ws + 2490368);
    const size_t PL = (size_t)NB*NP;
    float* plane = (float*)(ws + 4194304);
    float* b0  = plane;          // gauss tmp
    float* b1  = plane + PL;     // enh
    float* h0c = plane + 2*PL; float* h0s = plane + 3*PL;
    float* h1c = plane + 4*PL; float* h3c = plane + 5*PL;
    float* f0  = plane + 8*PL; float* f1 = plane + 9*PL;
    float* f2  = plane + 10*PL; float* f3 = plane + 11*PL;

    const float* gpadH = wtab;
    const float* gpadV = wtab + 128;

    initK<<<1, 256, 0, stream>>>(wtab, sc);
    reduceK<<<dim3(64, 8), 256, 0, stream>>>(img, pred, sc);

    dim3 gRow(768, 8);
    gaussHK2<<<gRow, 192, 0, stream>>>(img, b0, gpadH, sc);
    gaussVK4<<<2304, 128, 0, stream>>>(b0, img, b1, gpadV, sc);

    sobelK<<<18432, 256, 0, stream>>>(b1, maskB);

    gaborHF4<<<gRow, 192, 0, stream>>>(b1, h0c, h0s, h1c, h3c, wtab);

    gaborVAB<<<2304, 128, 0, stream>>>(h0c, h0s, f0, f2,
                                       wtab + 768, wtab + 896,
                                       p12, p12 + 2*P12N);
    gaborV13<<<2304, 128, 0, stream>>>(h1c, h3c, f1, f3,
                                       wtab + 1024, wtab + 1408,
                                       p12 + P12N, p12 + 3*P12N);
    sumKAll<<<dim3(8, 4), 256, 0, stream>>>(p12, fsum);

    seedK4<<<1152, 256, 0, stream>>>(f0, f1, f2, f3, fsum, seedB);

    for (int t = 0; t < FLOOD_PASSES; t++)
        floodTileK<<<dim3(3, 8), 256, 0, stream>>>(maskB, seedB, reachB, chg, t);

    finalK<<<dim3(3, H, 8), 256, 0, stream>>>(pred, reachB, sc, out);
}

// Round 13
// 245.361 us; speedup vs baseline: 1.3531x; 1.0113x over previous
//
#include <hip/hip_runtime.h>
#include <math.h>

typedef unsigned long long u64;

#define W 768
#define H 768
#define NP (768*768)
#define NB 8
#define WPR 12              // u64 words per row (768/64)
#define NW (NB*H*WPR)       // total words per bit buffer = 73728
#define TH 16               // output rows per block in tiled vertical convs
#define P12N 73728          // floats per p12 angle region (8*768*12)
#define FLOOD_PASSES 6

#define PADI(q) ((q) + ((q) >> 5))   // LDS pad: +1 word per 32

// ---------- ws layout (bytes) ----------
// 1024    : wtab (floats, 1536 entries):
//           [0..115] gpadH8 (tap j at [7+j], 101 real taps, zero-padded to 116)
//           [128..290] gpadV (tap j at [31+j])
//           [384+p*64]  H tables, d = i-27, real |d|<=r: p:0=h0c 1=h0s 2=h1c 5=h3c
//           [768+q*128] V tables (tap j at [31+j], zero-padded):
//                q: 0=v0c(R12) 1=v0s(R12) 2=v1c(R17) 5=v3c(R17)
// 16384   : sc (u32): [0..7] imgMinEnc [8..15] imgMaxEnc [16..23] predMinEnc
//           [24..31] predMaxEnc [32..63] fsum(f32) [64..127] chg flags
// 20480   : p12[4 angles][73728] f32
// 1310720 : maskBits u64[NW]
// 1900544 : seedBits u64[NW]
// 2490368 : reachBits u64[NW]
// 4 MiB   : planes: 0:b0(tmp) 1:b1(enh) 2:h0c 3:h0s 4:h1c 5:h3c 8:f0 9:f1 10:f2 11:f3

__device__ __forceinline__ unsigned fenc(float f) {
    unsigned b = __float_as_uint(f);
    return b ^ ((unsigned)((int)b >> 31) | 0x80000000u);
}
__device__ __forceinline__ float fdec(unsigned u) {
    unsigned b = (u & 0x80000000u) ? (u ^ 0x80000000u) : ~u;
    return __uint_as_float(b);
}
__device__ __forceinline__ int refl101(int i, int n) {
    if (i < 0) i = -i;
    if (i >= n) i = 2*n - 2 - i;
    return i;
}
__device__ __forceinline__ int symref(int i, int n) {
    if (i < 0) i = -1 - i;
    if (i >= n) i = 2*n - 1 - i;
    return i;
}

// ---------------- init: parallel weight tables + scalar init ----------------
__global__ void initK(float* wtab, unsigned* sc) {
    int t = threadIdx.x;
    __shared__ double gd[101];
    __shared__ double ssumS;
    const double sig = 15.5;
    if (t < 101) { double xx = t - 50; gd[t] = exp(-xx*xx/(2.0*sig*sig)); }
    __syncthreads();
    if (t == 0) {
        double s = 0.0;                       // identical sequential order -> identical ssum
        for (int i = 0; i < 101; i++) s += gd[i];
        ssumS = s;
    }
    __syncthreads();
    double ssum = ssumS;
    for (int i = t; i < 116; i += 256) {      // gpadH8: tap j at [7+j]
        float v = 0.f; int j = i - 7;
        if (j >= 0 && j < 101) v = (float)(gd[j]/ssum);
        wtab[i] = v;
    }
    for (int i = t; i < 163; i += 256) {      // gpadV: tap j at [31+j]
        float v = 0.f; int j = i - 31;
        if (j >= 0 && j < 101) v = (float)(gd[j]/ssum);
        wtab[128 + i] = v;
    }
    const double thetas[4] = {45.0, 90.0, 135.0, 180.0};
    const int    rad[4]    = {12, 17, 12, 17};
    const double sg = ((1.0/M_PI) * sqrt(log(2.0)/2.0) * 3.0) / 0.1;
    const double C  = 1.0/(2.0*M_PI*sg*sg);
    const int hG[6]   = {0, 0, 1, 2, 2, 3};
    const int hSin[6] = {0, 1, 0, 0, 1, 0};
    for (int idx = t; idx < 6*64; idx += 256) {   // H tables: d = i-27
        int p = idx / 64, i = idx % 64;
        int g = hG[p], r = rad[g];
        double th = thetas[g] * (M_PI / 180.0);
        double a  = 2.0*M_PI*0.1*cos(th);
        float v = 0.f;
        int d = i - 27;
        if (d >= -r && d <= r) {
            double dd = (double)d, G = exp(-0.5*dd*dd/(sg*sg));
            v = hSin[p] ? (float)(C*G*sin(a*dd)) : (float)(C*G*cos(a*dd));
        }
        wtab[384 + p*64 + i] = v;
    }
    const int vG[6]   = {0, 0, 1, 2, 2, 3};
    const int vSin[6] = {0, 1, 0, 0, 1, 0};
    for (int idx = t; idx < 6*128; idx += 256) {
        int q = idx / 128, i = idx % 128;
        int g = vG[q], r = rad[g];
        double th = thetas[g] * (M_PI / 180.0);
        double bb = 2.0*M_PI*0.1*sin(th);
        float v = 0.f;
        int j = i - 31;
        if (j >= 0 && j <= 2*r) {
            double dd = (double)(j - r), G = exp(-0.5*dd*dd/(sg*sg));
            v = vSin[q] ? (float)(G*sin(bb*dd)) : (float)(G*cos(bb*dd));
        }
        wtab[768 + q*128 + i] = v;
    }
    if (t < 8)  { sc[t] = 0xFFFFFFFFu; sc[8+t] = 0u; sc[16+t] = 0xFFFFFFFFu; sc[24+t] = 0u; }
    if (t >= 32 && t < 64) ((float*)sc)[t] = 0.f;        // fsum
    if (t >= 64 && t < 128) sc[t] = 0u;                  // chg flags
}

// ---------------- per-image min/max of img and pred ----------------
__global__ void reduceK(const float* __restrict__ img, const float* __restrict__ pred,
                        unsigned* sc) {
    int b = blockIdx.y;
    int base = b*NP + blockIdx.x*9216 + threadIdx.x;
    float imn = INFINITY, imx = -INFINITY, pmn = INFINITY, pmx = -INFINITY;
    for (int k = 0; k < 36; k++) {
        float v = img[base + k*256];  imn = fminf(imn, v); imx = fmaxf(imx, v);
        float p = pred[base + k*256]; pmn = fminf(pmn, p); pmx = fmaxf(pmx, p);
    }
    for (int off = 32; off; off >>= 1) {
        imn = fminf(imn, __shfl_down(imn, off));
        imx = fmaxf(imx, __shfl_down(imx, off));
        pmn = fminf(pmn, __shfl_down(pmn, off));
        pmx = fmaxf(pmx, __shfl_down(pmx, off));
    }
    __shared__ float s[4][4];
    int lane = threadIdx.x & 63, wv = threadIdx.x >> 6;
    if (lane == 0) { s[0][wv] = imn; s[1][wv] = imx; s[2][wv] = pmn; s[3][wv] = pmx; }
    __syncthreads();
    if (threadIdx.x == 0) {
        float a0 = s[0][0], a1 = s[1][0], a2 = s[2][0], a3 = s[3][0];
        for (int w = 1; w < 4; w++) {
            a0 = fminf(a0, s[0][w]); a1 = fmaxf(a1, s[1][w]);
            a2 = fminf(a2, s[2][w]); a3 = fmaxf(a3, s[3][w]);
        }
        atomicMin(&sc[b],      fenc(a0));
        atomicMax(&sc[8 + b],  fenc(a1));
        atomicMin(&sc[16 + b], fenc(a2));
        atomicMax(&sc[24 + b], fenc(a3));
    }
}

// ------- Gaussian blur H: 8 outputs/thread, 2 rows/block, padded LDS -------
__global__ __launch_bounds__(192) void gaussHK3(const float* __restrict__ img,
                                                float* __restrict__ out,
                                                const float* __restrict__ wt,
                                                const unsigned* __restrict__ sc) {
    int b = blockIdx.y, y0 = blockIdx.x*2, t = threadIdx.x;
    float mn = fdec(sc[b]), mx = fdec(sc[8 + b]);
    float den = mx - mn;
    __shared__ float sh[2][896];
    const float* rowA = img + ((size_t)b*H + y0)*W;
    const float* rowB = rowA + W;
    for (int q = t; q < 868; q += 192) {
        int gx = refl101(q - 50, W);
        sh[0][PADI(q)] = (rowA[gx] - mn) / den;
        sh[1][PADI(q)] = (rowB[gx] - mn) / den;
    }
    __syncthreads();
    int rsel = t >= 96 ? 1 : 0;
    int tt = t - 96*rsel;
    int qb = 8*tt;
    const float* S = sh[rsel];
    float a[8];
    #pragma unroll
    for (int i = 0; i < 8; i++) a[i] = 0.f;
    #pragma unroll 4
    for (int p = 0; p < 108; p++) {
        float v = S[PADI(qb + p)];
        #pragma unroll
        for (int sub = 0; sub < 8; sub++)
            a[sub] = __fmaf_rn(wt[p + 7 - sub], v, a[sub]);
    }
    size_t o = ((size_t)b*H + y0 + rsel)*W + qb;
    *(float4*)(out + o)     = make_float4(a[0], a[1], a[2], a[3]);
    *(float4*)(out + o + 4) = make_float4(a[4], a[5], a[6], a[7]);
}

// ---------------- Gaussian blur V: unroll x4, XCD-resident image ----------------
__global__ __launch_bounds__(128) void gaussVK4(const float* __restrict__ tmp,
                                                const float* __restrict__ img,
                                                float* __restrict__ enh,
                                                const float* __restrict__ wt,
                                                const unsigned* __restrict__ sc) {
    int bid = blockIdx.x;
    int b = bid & 7; int r_ = bid >> 3; int tile = r_ % 48; int strip = r_ / 48;
    int y0 = tile*TH, x = strip*128 + threadIdx.x;
    float acc[TH];
    #pragma unroll
    for (int k = 0; k < TH; k++) acc[k] = 0.f;
    const float* T = tmp + (size_t)b*NP;
    for (int base = 0; base < 116; base += 4) {
        int g0 = refl101(y0+base-50, H), g1 = refl101(y0+base-49, H),
            g2 = refl101(y0+base-48, H), g3 = refl101(y0+base-47, H);
        float v0 = T[g0*W+x], v1 = T[g1*W+x], v2 = T[g2*W+x], v3 = T[g3*W+x];
        #pragma unroll
        for (int k = 0; k < TH; k++) {
            float a = acc[k];
            a = __fmaf_rn(wt[base   -k+31], v0, a);
            a = __fmaf_rn(wt[base+1 -k+31], v1, a);
            a = __fmaf_rn(wt[base+2 -k+31], v2, a);
            a = __fmaf_rn(wt[base+3 -k+31], v3, a);
            acc[k] = a;
        }
    }
    float mn = fdec(sc[b]), mx = fdec(sc[8 + b]);
    float den = mx - mn;
    #pragma unroll
    for (int k = 0; k < TH; k++) {
        size_t o = ((size_t)b*H + y0 + k)*W + x;
        float vv = (img[o] - mn) / den;
        float e = vv - acc[k];
        e = fminf(fmaxf(e, 0.f), 1.f);
        enh[o] = e;
    }
}

// ------- fused Gabor H: 4 planes, 8 outputs/thread, 2 rows/block -------
__global__ __launch_bounds__(192) void gaborHF8(const float* __restrict__ enh,
        float* __restrict__ h0c, float* __restrict__ h0s,
        float* __restrict__ h1c, float* __restrict__ h3c,
        const float* __restrict__ wt) {
    int b = blockIdx.y, y0 = blockIdx.x*2, t = threadIdx.x;
    __shared__ float sh[2][840];
    const float* rowA = enh + ((size_t)b*H + y0)*W;
    const float* rowB = rowA + W;
    for (int q = t; q < 812; q += 192) {
        int gx = symref(q - 20, W);
        sh[0][PADI(q)] = rowA[gx];
        sh[1][PADI(q)] = rowB[gx];
    }
    __syncthreads();
    const float* T0c = wt + 384; const float* T0s = wt + 448;
    const float* T1c = wt + 512; const float* T3c = wt + 704;
    int rsel = t >= 96 ? 1 : 0;
    int tt = t - 96*rsel;
    int qb = 8*tt;
    const float* S = sh[rsel];
    float a0c[8], a0s[8], a1c[8], a3c[8];
    #pragma unroll
    for (int i = 0; i < 8; i++) { a0c[i] = 0.f; a0s[i] = 0.f; a1c[i] = 0.f; a3c[i] = 0.f; }
    #pragma unroll 4
    for (int p = 0; p < 52; p++) {
        float v = S[PADI(qb + p)];
        #pragma unroll
        for (int sub = 0; sub < 8; sub++) {
            int idx = p + 7 - sub;
            a0c[sub] = __fmaf_rn(T0c[idx], v, a0c[sub]);
            a0s[sub] = __fmaf_rn(T0s[idx], v, a0s[sub]);
            a1c[sub] = __fmaf_rn(T1c[idx], v, a1c[sub]);
            a3c[sub] = __fmaf_rn(T3c[idx], v, a3c[sub]);
        }
    }
    size_t o = ((size_t)b*H + y0 + rsel)*W + qb;
    *(float4*)(h0c + o)     = make_float4(a0c[0], a0c[1], a0c[2], a0c[3]);
    *(float4*)(h0c + o + 4) = make_float4(a0c[4], a0c[5], a0c[6], a0c[7]);
    *(float4*)(h0s + o)     = make_float4(a0s[0], a0s[1], a0s[2], a0s[3]);
    *(float4*)(h0s + o + 4) = make_float4(a0s[4], a0s[5], a0s[6], a0s[7]);
    *(float4*)(h1c + o)     = make_float4(a1c[0], a1c[1], a1c[2], a1c[3]);
    *(float4*)(h1c + o + 4) = make_float4(a1c[4], a1c[5], a1c[6], a1c[7]);
    *(float4*)(h3c + o)     = make_float4(a3c[0], a3c[1], a3c[2], a3c[3]);
    *(float4*)(h3c + o + 4) = make_float4(a3c[4], a3c[5], a3c[6], a3c[7]);
}

// ------- Gabor V, 45/135 pair: A=Vc*hc, B=Vs*hs -> f0=A-B, f2=A+B (unroll x4) -------
__global__ __launch_bounds__(128) void gaborVAB(
        const float* __restrict__ hc, const float* __restrict__ hs,
        float* __restrict__ f0, float* __restrict__ f2,
        const float* __restrict__ Tc, const float* __restrict__ Ts,
        float* __restrict__ p0, float* __restrict__ p2) {
    int bid = blockIdx.x;
    int b = bid & 7; int r_ = bid >> 3; int tile = r_ % 48; int strip = r_ / 48;
    int y0 = tile*TH, x = strip*128 + threadIdx.x;
    float A[TH], Bm[TH];
    #pragma unroll
    for (int k = 0; k < TH; k++) { A[k] = 0.f; Bm[k] = 0.f; }
    const size_t pb = (size_t)b*NP;
    for (int base = 0; base < 48; base += 4) {
        int g0 = symref(y0 + base - 17, H), g1 = symref(y0 + base - 16, H);
        int g2 = symref(y0 + base - 15, H), g3 = symref(y0 + base - 14, H);
        size_t o0 = pb + (size_t)g0*W + x, o1 = pb + (size_t)g1*W + x;
        size_t o2 = pb + (size_t)g2*W + x, o3 = pb + (size_t)g3*W + x;
        float vc0 = hc[o0], vc1 = hc[o1], vc2 = hc[o2], vc3 = hc[o3];
        float vs0 = hs[o0], vs1 = hs[o1], vs2 = hs[o2], vs3 = hs[o3];
        #pragma unroll
        for (int k = 0; k < TH; k++) {
            int i26 = base - k + 26;
            float t = A[k];
            t = __fmaf_rn(Tc[i26],   vc0, t);
            t = __fmaf_rn(Tc[i26+1], vc1, t);
            t = __fmaf_rn(Tc[i26+2], vc2, t);
            t = __fmaf_rn(Tc[i26+3], vc3, t);
            A[k] = t;
            t = Bm[k];
            t = __fmaf_rn(Ts[i26],   vs0, t);
            t = __fmaf_rn(Ts[i26+1], vs1, t);
            t = __fmaf_rn(Ts[i26+2], vs2, t);
            t = __fmaf_rn(Ts[i26+3], vs3, t);
            Bm[k] = t;
        }
    }
    {   // remainder rows: base = 48, 49
        int g0 = symref(y0 + 31, H), g1 = symref(y0 + 32, H);
        size_t o0 = pb + (size_t)g0*W + x, o1 = pb + (size_t)g1*W + x;
        float vc0 = hc[o0], vc1 = hc[o1];
        float vs0 = hs[o0], vs1 = hs[o1];
        #pragma unroll
        for (int k = 0; k < TH; k++) {
            int i26 = 48 - k + 26;
            float t = A[k];
            t = __fmaf_rn(Tc[i26],   vc0, t);
            t = __fmaf_rn(Tc[i26+1], vc1, t);
            A[k] = t;
            t = Bm[k];
            t = __fmaf_rn(Ts[i26],   vs0, t);
            t = __fmaf_rn(Ts[i26+1], vs1, t);
            Bm[k] = t;
        }
    }
    int g64 = strip*2 + (threadIdx.x >> 6);
    bool l0 = (threadIdx.x & 63) == 0;
    #pragma unroll
    for (int k = 0; k < TH; k++) {
        size_t o = ((size_t)b*H + y0 + k)*W + x;
        size_t po = ((size_t)b*H + y0 + k)*12 + g64;
        float v0 = A[k] - Bm[k];
        float v2 = A[k] + Bm[k];
        f0[o] = v0;
        float s = v0;
        for (int off = 32; off; off >>= 1) s += __shfl_down(s, off);
        if (l0) p0[po] = s;
        f2[o] = v2;
        s = v2;
        for (int off = 32; off; off >>= 1) s += __shfl_down(s, off);
        if (l0) p2[po] = s;
    }
}

// ------- Gabor V, 90/180 pair: two independent 1-plane chains (unroll x4) -------
__global__ __launch_bounds__(128) void gaborV13(
        const float* __restrict__ h1, const float* __restrict__ h3,
        float* __restrict__ f1, float* __restrict__ f3,
        const float* __restrict__ T1, const float* __restrict__ T3,
        float* __restrict__ p1, float* __restrict__ p3) {
    int bid = blockIdx.x;
    int b = bid & 7; int r_ = bid >> 3; int tile = r_ % 48; int strip = r_ / 48;
    int y0 = tile*TH, x = strip*128 + threadIdx.x;
    float a1[TH], a3[TH];
    #pragma unroll
    for (int k = 0; k < TH; k++) { a1[k] = 0.f; a3[k] = 0.f; }
    const size_t pb = (size_t)b*NP;
    for (int base = 0; base < 48; base += 4) {
        int g0 = symref(y0 + base - 17, H), g1 = symref(y0 + base - 16, H);
        int g2 = symref(y0 + base - 15, H), g3 = symref(y0 + base - 14, H);
        size_t o0 = pb + (size_t)g0*W + x, o1 = pb + (size_t)g1*W + x;
        size_t o2 = pb + (size_t)g2*W + x, o3 = pb + (size_t)g3*W + x;
        float v10 = h1[o0], v11 = h1[o1], v12 = h1[o2], v13 = h1[o3];
        float v30 = h3[o0], v31 = h3[o1], v32 = h3[o2], v33 = h3[o3];
        #pragma unroll
        for (int k = 0; k < TH; k++) {
            int i31 = base - k + 31;
            float t = a1[k];
            t = __fmaf_rn(T1[i31],   v10, t);
            t = __fmaf_rn(T1[i31+1], v11, t);
            t = __fmaf_rn(T1[i31+2], v12, t);
            t = __fmaf_rn(T1[i31+3], v13, t);
            a1[k] = t;
            t = a3[k];
            t = __fmaf_rn(T3[i31],   v30, t);
            t = __fmaf_rn(T3[i31+1], v31, t);
            t = __fmaf_rn(T3[i31+2], v32, t);
            t = __fmaf_rn(T3[i31+3], v33, t);
            a3[k] = t;
        }
    }
    {   // remainder rows: base = 48, 49
        int g0 = symref(y0 + 31, H), g1 = symref(y0 + 32, H);
        size_t o0 = pb + (size_t)g0*W + x, o1 = pb + (size_t)g1*W + x;
        float v10 = h1[o0], v11 = h1[o1];
        float v30 = h3[o0], v31 = h3[o1];
        #pragma unroll
        for (int k = 0; k < TH; k++) {
            int i31 = 48 - k + 31;
            float t = a1[k];
            t = __fmaf_rn(T1[i31],   v10, t);
            t = __fmaf_rn(T1[i31+1], v11, t);
            a1[k] = t;
            t = a3[k];
            t = __fmaf_rn(T3[i31],   v30, t);
            t = __fmaf_rn(T3[i31+1], v31, t);
            a3[k] = t;
        }
    }
    int g64 = strip*2 + (threadIdx.x >> 6);
    bool l0 = (threadIdx.x & 63) == 0;
    #pragma unroll
    for (int k = 0; k < TH; k++) {
        size_t o = ((size_t)b*H + y0 + k)*W + x;
        size_t po = ((size_t)b*H + y0 + k)*12 + g64;
        f1[o] = a1[k];
        float s = a1[k];
        for (int off = 32; off; off >>= 1) s += __shfl_down(s, off);
        if (l0) p1[po] = s;
        f3[o] = a3[k];
        s = a3[k];
        for (int off = 32; off; off >>= 1) s += __shfl_down(s, off);
        if (l0) p3[po] = s;
    }
}

// ---------------- deterministic per-image sums, all 4 angles ----------------
__global__ void sumKAll(const float* __restrict__ p12, float* fsum) {
    int b = blockIdx.x, g = blockIdx.y, t = threadIdx.x;
    const float* P = p12 + (size_t)g*P12N;
    float s = 0.f;
    for (int k = 0; k < 9; k++) {
        int idx = t + k*256;                 // 0..2303 == row*3 + strip
        int row = idx / 3, strip = idx - row*3;
        const float* Q = P + ((size_t)b*H + row)*12 + strip*4;
        float p4 = ((Q[0] + Q[1]) + Q[2]) + Q[3];
        s += p4;
    }
    __shared__ float sm[256];
    sm[t] = s; __syncthreads();
    for (int off = 128; off; off >>= 1) {
        if (t < off) sm[t] += sm[t + off];
        __syncthreads();
    }
    if (t == 0) fsum[g*8 + b] = sm[0];
}

// ---------------- seeds: row-tiled, 4 planes sequential in LDS (XCD swizzle) ----------------
__global__ __launch_bounds__(256) void seedK4(const float* __restrict__ f0,
        const float* __restrict__ f1, const float* __restrict__ f2,
        const float* __restrict__ f3, const float* __restrict__ fsum,
        u64* __restrict__ seedB) {
    int bid = blockIdx.x;
    int b = bid & 7; int r_ = bid >> 3;          // 0..143
    int y0 = (r_ % 48)*16; int xb = r_ / 48;     // 0..2
    int x0 = xb*256, t = threadIdx.x;
    __shared__ float sh[18][258];
    const float* planes[4] = {f0, f1, f2, f3};
    unsigned condMask = 0;
    #pragma unroll
    for (int a = 0; a < 4; a++) {
        const float* F = planes[a] + (size_t)b*NP;
        __syncthreads();
        for (int idx = t; idx < 18*258; idx += 256) {
            int rr = idx / 258, q = idx - rr*258;
            int gy = y0 - 1 + rr; gy = gy < 0 ? 0 : (gy > H-1 ? H-1 : gy);
            int gx = x0 - 1 + q;  gx = gx < 0 ? 0 : (gx > W-1 ? W-1 : gx);
            sh[rr][q] = F[gy*W + gx];
        }
        __syncthreads();
        float mean = fsum[a*8 + b] / 589824.f;
        #pragma unroll
        for (int r = 0; r < 16; r++) {
            float c = sh[r+1][t+1];
            float mx = c;
            mx = fmaxf(mx, sh[r  ][t]); mx = fmaxf(mx, sh[r  ][t+1]); mx = fmaxf(mx, sh[r  ][t+2]);
            mx = fmaxf(mx, sh[r+1][t]); mx = fmaxf(mx, sh[r+1][t+1]); mx = fmaxf(mx, sh[r+1][t+2]);
            mx = fmaxf(mx, sh[r+2][t]); mx = fmaxf(mx, sh[r+2][t+1]); mx = fmaxf(mx, sh[r+2][t+2]);
            if ((c == mx) && (c > mean)) condMask |= (1u << r);
        }
    }
    int wv = t >> 6, lane = t & 63;
    #pragma unroll
    for (int r = 0; r < 16; r++) {
        u64 m = __ballot((condMask >> r) & 1u);
        if (lane == 0)
            seedB[((size_t)b*H + y0 + r)*WPR + xb*4 + wv] = m;
    }
}

// ---------------- Sobel grad mask (bitpacked, XCD swizzle) ----------------
__global__ void sobelK(const float* __restrict__ enh, u64* __restrict__ maskB) {
    int bid = blockIdx.x;
    int b = bid & 7; int r_ = bid >> 3;     // 0..2303
    int y = r_ / 3; int xs = r_ - 3*y;
    int x = xs*256 + threadIdx.x;
    const float* E = enh + (size_t)b*NP;
    int ym = y > 0 ? y-1 : 1, yp = y < H-1 ? y+1 : H-2;   // reflect101
    int xm = x > 0 ? x-1 : 1, xp = x < W-1 ? x+1 : W-2;
    float a00 = E[ym*W + xm], a01 = E[ym*W + x], a02 = E[ym*W + xp];
    float a10 = E[y*W + xm],                     a12 = E[y*W + xp];
    float a20 = E[yp*W + xm], a21 = E[yp*W + x], a22 = E[yp*W + xp];
    float gx = __fmaf_rn(-1.f, a00, 0.f);
    gx = __fmaf_rn( 1.f, a02, gx);
    gx = __fmaf_rn(-2.f, a10, gx);
    gx = __fmaf_rn( 2.f, a12, gx);
    gx = __fmaf_rn(-1.f, a20, gx);
    gx = __fmaf_rn( 1.f, a22, gx);
    float gy = __fmaf_rn(-1.f, a00, 0.f);
    gy = __fmaf_rn(-2.f, a01, gy);
    gy = __fmaf_rn(-1.f, a02, gy);
    gy = __fmaf_rn( 1.f, a20, gy);
    gy = __fmaf_rn( 2.f, a21, gy);
    gy = __fmaf_rn( 1.f, a22, gy);
    float s = __fadd_rn(__fmul_rn(gx, gx), __fmul_rn(gy, gy));
    float grad = (float)sqrt((double)s);
    const float THR = (float)(0.0789 + 1.0*0.0774);
    bool m = grad >= THR;
    u64 bits = __ballot(m);
    if ((threadIdx.x & 63) == 0) {
        int word = xs*4 + (threadIdx.x >> 6);
        maskB[((size_t)b*H + y)*WPR + word] = bits;
    }
}

// ------- flood: thread-per-row tiles (256 rows), O(1) horizontal run-fill, guarded passes -------
__global__ __launch_bounds__(256) void floodTileK(const u64* __restrict__ Mb,
        const u64* __restrict__ seedB, u64* __restrict__ Rb,
        unsigned* __restrict__ chg, int t) {
    if (t > 0 && chg[t-1] == 0) return;
    int b = blockIdx.y;
    int y0 = blockIdx.x * 256;
    int ty = threadIdx.x;
    int y = y0 + ty;
    const u64* M = Mb + (size_t)b*H*WPR;
    const u64* S = seedB + (size_t)b*H*WPR;
    u64* R = Rb + (size_t)b*H*WPR;
    u64 m[12], r[12], hT[12], hB[12];
    #pragma unroll
    for (int w = 0; w < 12; w++) {
        m[w] = M[y*WPR + w];
        r[w] = (t == 0) ? (m[w] & S[y*WPR + w]) : R[y*WPR + w];
    }
    bool topRow = (ty == 0), botRow = (ty == 255);
    #pragma unroll
    for (int w = 0; w < 12; w++) { hT[w] = 0ULL; hB[w] = 0ULL; }
    if (topRow && y0 > 0) {
        int hy = y0 - 1;
        #pragma unroll
        for (int w = 0; w < 12; w++)
            hT[w] = (t == 0) ? (M[hy*WPR+w] & S[hy*WPR+w]) : R[hy*WPR+w];
    }
    if (botRow && y0 + 256 < H) {
        int hy = y0 + 256;
        #pragma unroll
        for (int w = 0; w < 12; w++)
            hB[w] = (t == 0) ? (M[hy*WPR+w] & S[hy*WPR+w]) : R[hy*WPR+w];
    }
    __shared__ u64 L[256][12];
    __shared__ unsigned chgArr[4];
    #pragma unroll
    for (int w = 0; w < 12; w++) L[ty][w] = r[w];
    __syncthreads();
    int wvid = ty >> 6, lane = ty & 63;
    bool grew = false;
    while (true) {
        u64 D[12], F[12];
        #pragma unroll
        for (int w = 0; w < 12; w++) {
            u64 up = topRow ? hT[w] : L[ty-1][w];
            u64 dn = botRow ? hB[w] : L[ty+1][w];
            D[w] = r[w] | up | dn;
        }
        #pragma unroll
        for (int w = 0; w < 12; w++) {
            u64 s = D[w] | (D[w] << 1) | (D[w] >> 1);
            if (w > 0)  s |= D[w-1] >> 63;
            if (w < 11) s |= D[w+1] << 63;
            F[w] = s & m[w];
        }
        {
            u64 c = 0;
            #pragma unroll
            for (int w = 0; w < 12; w++) {
                u64 sd = (F[w] | c) & m[w];
                u64 uf = m[w] & ~(m[w] + sd);
                F[w] = uf | sd;
                c = uf >> 63;
            }
        }
        {
            u64 c = 0;
            #pragma unroll
            for (int w = 11; w >= 0; w--) {
                u64 sd = (F[w] | (c << 63)) & m[w];
                u64 bm = __brevll(m[w]);
                u64 df = __brevll(bm & ~(bm + __brevll(sd)));
                F[w] = df | sd;
                c = df & 1ULL;
            }
        }
        bool chgT = false;
        #pragma unroll
        for (int w = 0; w < 12; w++) if (F[w] != r[w]) chgT = true;
        bool wc = __any(chgT);
        if (lane == 0) chgArr[wvid] = wc ? 1u : 0u;
        __syncthreads();
        #pragma unroll
        for (int w = 0; w < 12; w++) { r[w] = F[w]; L[ty][w] = F[w]; }
        unsigned any = chgArr[0] | chgArr[1] | chgArr[2] | chgArr[3];
        __syncthreads();
        if (!any) break;
        grew = true;
    }
    #pragma unroll
    for (int w = 0; w < 12; w++) R[y*WPR + w] = r[w];
    if (grew && ty == 0) atomicOr(&chg[t], 1u);
}

// ---------------- final: out = (sigmoid?(pred)>0.5) | reach ----------------
__global__ void finalK(const float* __restrict__ pred, const u64* __restrict__ reachB,
                       const unsigned* __restrict__ sc, float* __restrict__ out) {
    int b = blockIdx.z, y = blockIdx.y, x = blockIdx.x*256 + threadIdx.x;
    float pmn = fdec(sc[16 + b]), pmx = fdec(sc[24 + b]);
    bool needSig = (pmx > 1.0f) || (pmn < 0.0f);
    float p = pred[((size_t)b*H + y)*W + x];
    float pv;
    if (needSig) {
        float e = (float)exp(-(double)p);
        pv = 1.f / (1.f + e);
    } else {
        pv = p;
    }
    bool on = pv > 0.5f;
    u64 w = reachB[((size_t)b*H + y)*WPR + (x >> 6)];
    on = on || ((w >> (x & 63)) & 1ULL);
    out[((size_t)b*H + y)*W + x] = on ? 1.f : 0.f;
}

extern "C" void kernel_launch(void* const* d_in, const int* in_sizes, int n_in,
                              void* d_out, int out_size, void* d_ws, size_t ws_size,
                              hipStream_t stream) {
    const float* pred = (const float*)d_in[0];
    const float* img  = (const float*)d_in[1];
    float* out = (float*)d_out;
    char* ws = (char*)d_ws;

    float*    wtab   = (float*)(ws + 1024);
    unsigned* sc     = (unsigned*)(ws + 16384);
    float*    fsum   = ((float*)sc) + 32;
    unsigned* chg    = sc + 64;
    float*    p12    = (float*)(ws + 20480);
    u64*      maskB  = (u64*)(ws + 1310720);
    u64*      seedB  = (u64*)(ws + 1900544);
    u64*      reachB = (u64*)(ws + 2490368);
    const size_t PL = (size_t)NB*NP;
    float* plane = (float*)(ws + 4194304);
    float* b0  = plane;          // gauss tmp
    float* b1  = plane + PL;     // enh
    float* h0c = plane + 2*PL; float* h0s = plane + 3*PL;
    float* h1c = plane + 4*PL; float* h3c = plane + 5*PL;
    float* f0  = plane + 8*PL; float* f1 = plane + 9*PL;
    float* f2  = plane + 10*PL; float* f3 = plane + 11*PL;

    const float* gpadH8 = wtab;
    const float* gpadV  = wtab + 128;

    initK<<<1, 256, 0, stream>>>(wtab, sc);
    reduceK<<<dim3(64, 8), 256, 0, stream>>>(img, pred, sc);

    gaussHK3<<<dim3(384, 8), 192, 0, stream>>>(img, b0, gpadH8, sc);
    gaussVK4<<<2304, 128, 0, stream>>>(b0, img, b1, gpadV, sc);

    sobelK<<<18432, 256, 0, stream>>>(b1, maskB);

    gaborHF8<<<dim3(384, 8), 192, 0, stream>>>(b1, h0c, h0s, h1c, h3c, wtab);

    gaborVAB<<<2304, 128, 0, stream>>>(h0c, h0s, f0, f2,
                                       wtab + 768, wtab + 896,
                                       p12, p12 + 2*P12N);
    gaborV13<<<2304, 128, 0, stream>>>(h1c, h3c, f1, f3,
                                       wtab + 1024, wtab + 1408,
                                       p12 + P12N, p12 + 3*P12N);
    sumKAll<<<dim3(8, 4), 256, 0, stream>>>(p12, fsum);

    seedK4<<<1152, 256, 0, stream>>>(f0, f1, f2, f3, fsum, seedB);

    for (int t = 0; t < FLOOD_PASSES; t++)
        floodTileK<<<dim3(3, 8), 256, 0, stream>>>(maskB, seedB, reachB, chg, t);

    finalK<<<dim3(3, H, 8), 256, 0, stream>>>(pred, reachB, sc, out);
}

// Round 14
// 243.737 us; speedup vs baseline: 1.3621x; 1.0067x over previous
//
#include <hip/hip_runtime.h>
#include <math.h>

typedef unsigned long long u64;

#define W 768
#define H 768
#define NP (768*768)
#define NB 8
#define WPR 12              // u64 words per row (768/64)
#define NW (NB*H*WPR)       // total words per bit buffer = 73728
#define TH 16               // output rows per block in tiled vertical convs
#define P12N 73728          // floats per p12 angle region (8*768*12)
#define FLOOD_PASSES 6

#define PADI(q) ((q) + ((q) >> 5))   // LDS pad: +1 word per 32

// ---------- ws layout (bytes) ----------
// 1024    : wtab (floats, 1536 entries):
//           [0..115] gpadH8 (tap j at [7+j], 101 real taps, zero-padded to 116)
//           [128..290] gpadV (tap j at [31+j])
//           [384+p*64]  H tables, d = i-27, real |d|<=r: p:0=h0c 1=h0s 2=h1c 5=h3c
//           [768+q*128] V tables (tap j at [31+j], zero-padded):
//                q: 0=v0c(R12) 1=v0s(R12) 2=v1c(R17) 5=v3c(R17)
// 16384   : sc (u32): [0..7] imgMinEnc [8..15] imgMaxEnc [16..23] predMinEnc
//           [24..31] predMaxEnc [32..63] fsum(f32) [64..127] chg flags
// 20480   : p12[4 angles][73728] f32
// 1310720 : maskBits u64[NW]
// 1900544 : seedBits u64[NW]
// 2490368 : reachBits u64[NW]
// 4 MiB   : planes: 0:b0(tmp) 1:b1(enh) 2:h0c 3:h0s 4:h1c 5:h3c 8:f0 9:f1 10:f2 11:f3

__device__ __forceinline__ unsigned fenc(float f) {
    unsigned b = __float_as_uint(f);
    return b ^ ((unsigned)((int)b >> 31) | 0x80000000u);
}
__device__ __forceinline__ float fdec(unsigned u) {
    unsigned b = (u & 0x80000000u) ? (u ^ 0x80000000u) : ~u;
    return __uint_as_float(b);
}
__device__ __forceinline__ int refl101(int i, int n) {
    if (i < 0) i = -i;
    if (i >= n) i = 2*n - 2 - i;
    return i;
}
__device__ __forceinline__ int symref(int i, int n) {
    if (i < 0) i = -1 - i;
    if (i >= n) i = 2*n - 1 - i;
    return i;
}

// ---------------- init: parallel weight tables + scalar init ----------------
__global__ void initK(float* wtab, unsigned* sc) {
    int t = threadIdx.x;
    __shared__ double gd[101];
    __shared__ double ssumS;
    const double sig = 15.5;
    if (t < 101) { double xx = t - 50; gd[t] = exp(-xx*xx/(2.0*sig*sig)); }
    __syncthreads();
    if (t == 0) {
        double s = 0.0;                       // identical sequential order -> identical ssum
        for (int i = 0; i < 101; i++) s += gd[i];
        ssumS = s;
    }
    __syncthreads();
    double ssum = ssumS;
    for (int i = t; i < 116; i += 256) {      // gpadH8: tap j at [7+j]
        float v = 0.f; int j = i - 7;
        if (j >= 0 && j < 101) v = (float)(gd[j]/ssum);
        wtab[i] = v;
    }
    for (int i = t; i < 163; i += 256) {      // gpadV: tap j at [31+j]
        float v = 0.f; int j = i - 31;
        if (j >= 0 && j < 101) v = (float)(gd[j]/ssum);
        wtab[128 + i] = v;
    }
    const double thetas[4] = {45.0, 90.0, 135.0, 180.0};
    const int    rad[4]    = {12, 17, 12, 17};
    const double sg = ((1.0/M_PI) * sqrt(log(2.0)/2.0) * 3.0) / 0.1;
    const double C  = 1.0/(2.0*M_PI*sg*sg);
    const int hG[6]   = {0, 0, 1, 2, 2, 3};
    const int hSin[6] = {0, 1, 0, 0, 1, 0};
    for (int idx = t; idx < 6*64; idx += 256) {   // H tables: d = i-27
        int p = idx / 64, i = idx % 64;
        int g = hG[p], r = rad[g];
        double th = thetas[g] * (M_PI / 180.0);
        double a  = 2.0*M_PI*0.1*cos(th);
        float v = 0.f;
        int d = i - 27;
        if (d >= -r && d <= r) {
            double dd = (double)d, G = exp(-0.5*dd*dd/(sg*sg));
            v = hSin[p] ? (float)(C*G*sin(a*dd)) : (float)(C*G*cos(a*dd));
        }
        wtab[384 + p*64 + i] = v;
    }
    const int vG[6]   = {0, 0, 1, 2, 2, 3};
    const int vSin[6] = {0, 1, 0, 0, 1, 0};
    for (int idx = t; idx < 6*128; idx += 256) {
        int q = idx / 128, i = idx % 128;
        int g = vG[q], r = rad[g];
        double th = thetas[g] * (M_PI / 180.0);
        double bb = 2.0*M_PI*0.1*sin(th);
        float v = 0.f;
        int j = i - 31;
        if (j >= 0 && j <= 2*r) {
            double dd = (double)(j - r), G = exp(-0.5*dd*dd/(sg*sg));
            v = vSin[q] ? (float)(G*sin(bb*dd)) : (float)(G*cos(bb*dd));
        }
        wtab[768 + q*128 + i] = v;
    }
    if (t < 8)  { sc[t] = 0xFFFFFFFFu; sc[8+t] = 0u; sc[16+t] = 0xFFFFFFFFu; sc[24+t] = 0u; }
    if (t >= 32 && t < 64) ((float*)sc)[t] = 0.f;        // fsum
    if (t >= 64 && t < 128) sc[t] = 0u;                  // chg flags
}

// ---------------- per-image min/max of img and pred ----------------
__global__ void reduceK(const float* __restrict__ img, const float* __restrict__ pred,
                        unsigned* sc) {
    int b = blockIdx.y;
    int base = b*NP + blockIdx.x*9216 + threadIdx.x;
    float imn = INFINITY, imx = -INFINITY, pmn = INFINITY, pmx = -INFINITY;
    for (int k = 0; k < 36; k++) {
        float v = img[base + k*256];  imn = fminf(imn, v); imx = fmaxf(imx, v);
        float p = pred[base + k*256]; pmn = fminf(pmn, p); pmx = fmaxf(pmx, p);
    }
    for (int off = 32; off; off >>= 1) {
        imn = fminf(imn, __shfl_down(imn, off));
        imx = fmaxf(imx, __shfl_down(imx, off));
        pmn = fminf(pmn, __shfl_down(pmn, off));
        pmx = fmaxf(pmx, __shfl_down(pmx, off));
    }
    __shared__ float s[4][4];
    int lane = threadIdx.x & 63, wv = threadIdx.x >> 6;
    if (lane == 0) { s[0][wv] = imn; s[1][wv] = imx; s[2][wv] = pmn; s[3][wv] = pmx; }
    __syncthreads();
    if (threadIdx.x == 0) {
        float a0 = s[0][0], a1 = s[1][0], a2 = s[2][0], a3 = s[3][0];
        for (int w = 1; w < 4; w++) {
            a0 = fminf(a0, s[0][w]); a1 = fmaxf(a1, s[1][w]);
            a2 = fminf(a2, s[2][w]); a3 = fmaxf(a3, s[3][w]);
        }
        atomicMin(&sc[b],      fenc(a0));
        atomicMax(&sc[8 + b],  fenc(a1));
        atomicMin(&sc[16 + b], fenc(a2));
        atomicMax(&sc[24 + b], fenc(a3));
    }
}

// ------- Gaussian blur H: 8 outputs/thread, 2 rows/block, padded LDS -------
__global__ __launch_bounds__(192) void gaussHK3(const float* __restrict__ img,
                                                float* __restrict__ out,
                                                const float* __restrict__ wt,
                                                const unsigned* __restrict__ sc) {
    int b = blockIdx.y, y0 = blockIdx.x*2, t = threadIdx.x;
    float mn = fdec(sc[b]), mx = fdec(sc[8 + b]);
    float den = mx - mn;
    __shared__ float sh[2][896];
    const float* rowA = img + ((size_t)b*H + y0)*W;
    const float* rowB = rowA + W;
    for (int q = t; q < 868; q += 192) {
        int gx = refl101(q - 50, W);
        sh[0][PADI(q)] = (rowA[gx] - mn) / den;
        sh[1][PADI(q)] = (rowB[gx] - mn) / den;
    }
    __syncthreads();
    int rsel = t >= 96 ? 1 : 0;
    int tt = t - 96*rsel;
    int qb = 8*tt;
    const float* S = sh[rsel];
    float a[8];
    #pragma unroll
    for (int i = 0; i < 8; i++) a[i] = 0.f;
    #pragma unroll 4
    for (int p = 0; p < 108; p++) {
        float v = S[PADI(qb + p)];
        #pragma unroll
        for (int sub = 0; sub < 8; sub++)
            a[sub] = __fmaf_rn(wt[p + 7 - sub], v, a[sub]);
    }
    size_t o = ((size_t)b*H + y0 + rsel)*W + qb;
    *(float4*)(out + o)     = make_float4(a[0], a[1], a[2], a[3]);
    *(float4*)(out + o + 4) = make_float4(a[4], a[5], a[6], a[7]);
}

// ---------------- Gaussian blur V: unroll x4, XCD-resident image ----------------
__global__ __launch_bounds__(128) void gaussVK4(const float* __restrict__ tmp,
                                                const float* __restrict__ img,
                                                float* __restrict__ enh,
                                                const float* __restrict__ wt,
                                                const unsigned* __restrict__ sc) {
    int bid = blockIdx.x;
    int b = bid & 7; int r_ = bid >> 3; int tile = r_ % 48; int strip = r_ / 48;
    int y0 = tile*TH, x = strip*128 + threadIdx.x;
    float acc[TH];
    #pragma unroll
    for (int k = 0; k < TH; k++) acc[k] = 0.f;
    const float* T = tmp + (size_t)b*NP;
    for (int base = 0; base < 116; base += 4) {
        int g0 = refl101(y0+base-50, H), g1 = refl101(y0+base-49, H),
            g2 = refl101(y0+base-48, H), g3 = refl101(y0+base-47, H);
        float v0 = T[g0*W+x], v1 = T[g1*W+x], v2 = T[g2*W+x], v3 = T[g3*W+x];
        #pragma unroll
        for (int k = 0; k < TH; k++) {
            float a = acc[k];
            a = __fmaf_rn(wt[base   -k+31], v0, a);
            a = __fmaf_rn(wt[base+1 -k+31], v1, a);
            a = __fmaf_rn(wt[base+2 -k+31], v2, a);
            a = __fmaf_rn(wt[base+3 -k+31], v3, a);
            acc[k] = a;
        }
    }
    float mn = fdec(sc[b]), mx = fdec(sc[8 + b]);
    float den = mx - mn;
    #pragma unroll
    for (int k = 0; k < TH; k++) {
        size_t o = ((size_t)b*H + y0 + k)*W + x;
        float vv = (img[o] - mn) / den;
        float e = vv - acc[k];
        e = fminf(fmaxf(e, 0.f), 1.f);
        enh[o] = e;
    }
}

// ------- fused Gabor H (4 planes, 8 out/thread, 2 rows/block) + Sobel mask -------
__global__ __launch_bounds__(192) void gaborHS8(const float* __restrict__ enh,
        float* __restrict__ h0c, float* __restrict__ h0s,
        float* __restrict__ h1c, float* __restrict__ h3c,
        const float* __restrict__ wt, u64* __restrict__ maskB) {
    int b = blockIdx.y, y0 = blockIdx.x*2, t = threadIdx.x;
    __shared__ float sh[4][840];
    __shared__ u64 words[24];
    const float* base = enh + (size_t)b*NP;
    int ra = (y0 == 0) ? 1 : y0 - 1;          // reflect101 row above pair
    int rb = (y0 + 2 <= H - 1) ? y0 + 2 : H - 2;   // row below pair (unused at y0=766 path)
    const float* rowm = base + (size_t)ra*W;
    const float* rowA = base + (size_t)y0*W;
    const float* rowB = rowA + W;
    const float* rowp = base + (size_t)rb*W;
    for (int q = t; q < 812; q += 192) {
        int gx = symref(q - 20, W);
        sh[0][PADI(q)] = rowm[gx];
        sh[1][PADI(q)] = rowA[gx];
        sh[2][PADI(q)] = rowB[gx];
        sh[3][PADI(q)] = rowp[gx];
    }
    if (t < 24) words[t] = 0ULL;
    __syncthreads();
    const float* T0c = wt + 384; const float* T0s = wt + 448;
    const float* T1c = wt + 512; const float* T3c = wt + 704;
    int rsel = t >= 96 ? 1 : 0;
    int tt = t - 96*rsel;
    int qb = 8*tt;
    const float* S = sh[1 + rsel];
    float a0c[8], a0s[8], a1c[8], a3c[8];
    #pragma unroll
    for (int i = 0; i < 8; i++) { a0c[i] = 0.f; a0s[i] = 0.f; a1c[i] = 0.f; a3c[i] = 0.f; }
    #pragma unroll 4
    for (int p = 0; p < 52; p++) {
        float v = S[PADI(qb + p)];
        #pragma unroll
        for (int sub = 0; sub < 8; sub++) {
            int idx = p + 7 - sub;
            a0c[sub] = __fmaf_rn(T0c[idx], v, a0c[sub]);
            a0s[sub] = __fmaf_rn(T0s[idx], v, a0s[sub]);
            a1c[sub] = __fmaf_rn(T1c[idx], v, a1c[sub]);
            a3c[sub] = __fmaf_rn(T3c[idx], v, a3c[sub]);
        }
    }
    size_t o = ((size_t)b*H + y0 + rsel)*W + qb;
    *(float4*)(h0c + o)     = make_float4(a0c[0], a0c[1], a0c[2], a0c[3]);
    *(float4*)(h0c + o + 4) = make_float4(a0c[4], a0c[5], a0c[6], a0c[7]);
    *(float4*)(h0s + o)     = make_float4(a0s[0], a0s[1], a0s[2], a0s[3]);
    *(float4*)(h0s + o + 4) = make_float4(a0s[4], a0s[5], a0s[6], a0s[7]);
    *(float4*)(h1c + o)     = make_float4(a1c[0], a1c[1], a1c[2], a1c[3]);
    *(float4*)(h1c + o + 4) = make_float4(a1c[4], a1c[5], a1c[6], a1c[7]);
    *(float4*)(h3c + o)     = make_float4(a3c[0], a3c[1], a3c[2], a3c[3]);
    *(float4*)(h3c + o + 4) = make_float4(a3c[4], a3c[5], a3c[6], a3c[7]);

    // ---- Sobel for this thread's 8 pixels (row y0+rsel), reflect101 ----
    // row slots: for rsel==0: ym=slot0, yp=slot2. for rsel==1: ym=slot1,
    //            yp = slot3, except y0==766 (y==767): yp = row766 = slot1.
    const float* Rm = sh[rsel == 0 ? 0 : 1];
    const float* Rc = sh[1 + rsel];
    const float* Rp = (rsel == 0) ? sh[2] : ((y0 == H - 2) ? sh[1] : sh[3]);
    unsigned byte = 0;
    #pragma unroll
    for (int sub = 0; sub < 8; sub++) {
        int c = qb + sub;
        int cm = (c > 0) ? c - 1 : 1;
        int cp = (c < W - 1) ? c + 1 : W - 2;
        int im = PADI(cm + 20), ic = PADI(c + 20), ip = PADI(cp + 20);
        float a00 = Rm[im], a01 = Rm[ic], a02 = Rm[ip];
        float a10 = Rc[im],               a12 = Rc[ip];
        float a20 = Rp[im], a21 = Rp[ic], a22 = Rp[ip];
        float gx = __fmaf_rn(-1.f, a00, 0.f);
        gx = __fmaf_rn( 1.f, a02, gx);
        gx = __fmaf_rn(-2.f, a10, gx);
        gx = __fmaf_rn( 2.f, a12, gx);
        gx = __fmaf_rn(-1.f, a20, gx);
        gx = __fmaf_rn( 1.f, a22, gx);
        float gy = __fmaf_rn(-1.f, a00, 0.f);
        gy = __fmaf_rn(-2.f, a01, gy);
        gy = __fmaf_rn(-1.f, a02, gy);
        gy = __fmaf_rn( 1.f, a20, gy);
        gy = __fmaf_rn( 2.f, a21, gy);
        gy = __fmaf_rn( 1.f, a22, gy);
        float s2 = __fadd_rn(__fmul_rn(gx, gx), __fmul_rn(gy, gy));
        float grad = (float)sqrt((double)s2);
        const float THR = (float)(0.0789 + 1.0*0.0774);
        if (grad >= THR) byte |= 1u << sub;
    }
    atomicOr(&words[rsel*12 + (qb >> 6)], (u64)byte << (qb & 63));
    __syncthreads();
    if (t < 24) {
        int row = y0 + (t / 12);
        maskB[((size_t)b*H + row)*WPR + (t % 12)] = words[t];
    }
}

// ------- Gabor V, 45/135 pair: A=Vc*hc, B=Vs*hs -> f0=A-B, f2=A+B (unroll x4) -------
__global__ __launch_bounds__(128) void gaborVAB(
        const float* __restrict__ hc, const float* __restrict__ hs,
        float* __restrict__ f0, float* __restrict__ f2,
        const float* __restrict__ Tc, const float* __restrict__ Ts,
        float* __restrict__ p0, float* __restrict__ p2) {
    int bid = blockIdx.x;
    int b = bid & 7; int r_ = bid >> 3; int tile = r_ % 48; int strip = r_ / 48;
    int y0 = tile*TH, x = strip*128 + threadIdx.x;
    float A[TH], Bm[TH];
    #pragma unroll
    for (int k = 0; k < TH; k++) { A[k] = 0.f; Bm[k] = 0.f; }
    const size_t pb = (size_t)b*NP;
    for (int base = 0; base < 48; base += 4) {
        int g0 = symref(y0 + base - 17, H), g1 = symref(y0 + base - 16, H);
        int g2 = symref(y0 + base - 15, H), g3 = symref(y0 + base - 14, H);
        size_t o0 = pb + (size_t)g0*W + x, o1 = pb + (size_t)g1*W + x;
        size_t o2 = pb + (size_t)g2*W + x, o3 = pb + (size_t)g3*W + x;
        float vc0 = hc[o0], vc1 = hc[o1], vc2 = hc[o2], vc3 = hc[o3];
        float vs0 = hs[o0], vs1 = hs[o1], vs2 = hs[o2], vs3 = hs[o3];
        #pragma unroll
        for (int k = 0; k < TH; k++) {
            int i26 = base - k + 26;
            float t = A[k];
            t = __fmaf_rn(Tc[i26],   vc0, t);
            t = __fmaf_rn(Tc[i26+1], vc1, t);
            t = __fmaf_rn(Tc[i26+2], vc2, t);
            t = __fmaf_rn(Tc[i26+3], vc3, t);
            A[k] = t;
            t = Bm[k];
            t = __fmaf_rn(Ts[i26],   vs0, t);
            t = __fmaf_rn(Ts[i26+1], vs1, t);
            t = __fmaf_rn(Ts[i26+2], vs2, t);
            t = __fmaf_rn(Ts[i26+3], vs3, t);
            Bm[k] = t;
        }
    }
    {   // remainder rows: base = 48, 49
        int g0 = symref(y0 + 31, H), g1 = symref(y0 + 32, H);
        size_t o0 = pb + (size_t)g0*W + x, o1 = pb + (size_t)g1*W + x;
        float vc0 = hc[o0], vc1 = hc[o1];
        float vs0 = hs[o0], vs1 = hs[o1];
        #pragma unroll
        for (int k = 0; k < TH; k++) {
            int i26 = 48 - k + 26;
            float t = A[k];
            t = __fmaf_rn(Tc[i26],   vc0, t);
            t = __fmaf_rn(Tc[i26+1], vc1, t);
            A[k] = t;
            t = Bm[k];
            t = __fmaf_rn(Ts[i26],   vs0, t);
            t = __fmaf_rn(Ts[i26+1], vs1, t);
            Bm[k] = t;
        }
    }
    int g64 = strip*2 + (threadIdx.x >> 6);
    bool l0 = (threadIdx.x & 63) == 0;
    #pragma unroll
    for (int k = 0; k < TH; k++) {
        size_t o = ((size_t)b*H + y0 + k)*W + x;
        size_t po = ((size_t)b*H + y0 + k)*12 + g64;
        float v0 = A[k] - Bm[k];
        float v2 = A[k] + Bm[k];
        f0[o] = v0;
        float s = v0;
        for (int off = 32; off; off >>= 1) s += __shfl_down(s, off);
        if (l0) p0[po] = s;
        f2[o] = v2;
        s = v2;
        for (int off = 32; off; off >>= 1) s += __shfl_down(s, off);
        if (l0) p2[po] = s;
    }
}

// ------- Gabor V, 90/180 pair: two independent 1-plane chains (unroll x4) -------
__global__ __launch_bounds__(128) void gaborV13(
        const float* __restrict__ h1, const float* __restrict__ h3,
        float* __restrict__ f1, float* __restrict__ f3,
        const float* __restrict__ T1, const float* __restrict__ T3,
        float* __restrict__ p1, float* __restrict__ p3) {
    int bid = blockIdx.x;
    int b = bid & 7; int r_ = bid >> 3; int tile = r_ % 48; int strip = r_ / 48;
    int y0 = tile*TH, x = strip*128 + threadIdx.x;
    float a1[TH], a3[TH];
    #pragma unroll
    for (int k = 0; k < TH; k++) { a1[k] = 0.f; a3[k] = 0.f; }
    const size_t pb = (size_t)b*NP;
    for (int base = 0; base < 48; base += 4) {
        int g0 = symref(y0 + base - 17, H), g1 = symref(y0 + base - 16, H);
        int g2 = symref(y0 + base - 15, H), g3 = symref(y0 + base - 14, H);
        size_t o0 = pb + (size_t)g0*W + x, o1 = pb + (size_t)g1*W + x;
        size_t o2 = pb + (size_t)g2*W + x, o3 = pb + (size_t)g3*W + x;
        float v10 = h1[o0], v11 = h1[o1], v12 = h1[o2], v13 = h1[o3];
        float v30 = h3[o0], v31 = h3[o1], v32 = h3[o2], v33 = h3[o3];
        #pragma unroll
        for (int k = 0; k < TH; k++) {
            int i31 = base - k + 31;
            float t = a1[k];
            t = __fmaf_rn(T1[i31],   v10, t);
            t = __fmaf_rn(T1[i31+1], v11, t);
            t = __fmaf_rn(T1[i31+2], v12, t);
            t = __fmaf_rn(T1[i31+3], v13, t);
            a1[k] = t;
            t = a3[k];
            t = __fmaf_rn(T3[i31],   v30, t);
            t = __fmaf_rn(T3[i31+1], v31, t);
            t = __fmaf_rn(T3[i31+2], v32, t);
            t = __fmaf_rn(T3[i31+3], v33, t);
            a3[k] = t;
        }
    }
    {   // remainder rows: base = 48, 49
        int g0 = symref(y0 + 31, H), g1 = symref(y0 + 32, H);
        size_t o0 = pb + (size_t)g0*W + x, o1 = pb + (size_t)g1*W + x;
        float v10 = h1[o0], v11 = h1[o1];
        float v30 = h3[o0], v31 = h3[o1];
        #pragma unroll
        for (int k = 0; k < TH; k++) {
            int i31 = 48 - k + 31;
            float t = a1[k];
            t = __fmaf_rn(T1[i31],   v10, t);
            t = __fmaf_rn(T1[i31+1], v11, t);
            a1[k] = t;
            t = a3[k];
            t = __fmaf_rn(T3[i31],   v30, t);
            t = __fmaf_rn(T3[i31+1], v31, t);
            a3[k] = t;
        }
    }
    int g64 = strip*2 + (threadIdx.x >> 6);
    bool l0 = (threadIdx.x & 63) == 0;
    #pragma unroll
    for (int k = 0; k < TH; k++) {
        size_t o = ((size_t)b*H + y0 + k)*W + x;
        size_t po = ((size_t)b*H + y0 + k)*12 + g64;
        f1[o] = a1[k];
        float s = a1[k];
        for (int off = 32; off; off >>= 1) s += __shfl_down(s, off);
        if (l0) p1[po] = s;
        f3[o] = a3[k];
        s = a3[k];
        for (int off = 32; off; off >>= 1) s += __shfl_down(s, off);
        if (l0) p3[po] = s;
    }
}

// ---------------- deterministic per-image sums, all 4 angles ----------------
__global__ void sumKAll(const float* __restrict__ p12, float* fsum) {
    int b = blockIdx.x, g = blockIdx.y, t = threadIdx.x;
    const float* P = p12 + (size_t)g*P12N;
    float s = 0.f;
    for (int k = 0; k < 9; k++) {
        int idx = t + k*256;                 // 0..2303 == row*3 + strip
        int row = idx / 3, strip = idx - row*3;
        const float* Q = P + ((size_t)b*H + row)*12 + strip*4;
        float p4 = ((Q[0] + Q[1]) + Q[2]) + Q[3];
        s += p4;
    }
    __shared__ float sm[256];
    sm[t] = s; __syncthreads();
    for (int off = 128; off; off >>= 1) {
        if (t < off) sm[t] += sm[t + off];
        __syncthreads();
    }
    if (t == 0) fsum[g*8 + b] = sm[0];
}

// ---------------- seeds: row-tiled, 4 planes sequential in LDS (XCD swizzle) ----------------
__global__ __launch_bounds__(256) void seedK4(const float* __restrict__ f0,
        const float* __restrict__ f1, const float* __restrict__ f2,
        const float* __restrict__ f3, const float* __restrict__ fsum,
        u64* __restrict__ seedB) {
    int bid = blockIdx.x;
    int b = bid & 7; int r_ = bid >> 3;          // 0..143
    int y0 = (r_ % 48)*16; int xb = r_ / 48;     // 0..2
    int x0 = xb*256, t = threadIdx.x;
    __shared__ float sh[18][258];
    const float* planes[4] = {f0, f1, f2, f3};
    unsigned condMask = 0;
    #pragma unroll
    for (int a = 0; a < 4; a++) {
        const float* F = planes[a] + (size_t)b*NP;
        __syncthreads();
        for (int idx = t; idx < 18*258; idx += 256) {
            int rr = idx / 258, q = idx - rr*258;
            int gy = y0 - 1 + rr; gy = gy < 0 ? 0 : (gy > H-1 ? H-1 : gy);
            int gx = x0 - 1 + q;  gx = gx < 0 ? 0 : (gx > W-1 ? W-1 : gx);
            sh[rr][q] = F[gy*W + gx];
        }
        __syncthreads();
        float mean = fsum[a*8 + b] / 589824.f;
        #pragma unroll
        for (int r = 0; r < 16; r++) {
            float c = sh[r+1][t+1];
            float mx = c;
            mx = fmaxf(mx, sh[r  ][t]); mx = fmaxf(mx, sh[r  ][t+1]); mx = fmaxf(mx, sh[r  ][t+2]);
            mx = fmaxf(mx, sh[r+1][t]); mx = fmaxf(mx, sh[r+1][t+1]); mx = fmaxf(mx, sh[r+1][t+2]);
            mx = fmaxf(mx, sh[r+2][t]); mx = fmaxf(mx, sh[r+2][t+1]); mx = fmaxf(mx, sh[r+2][t+2]);
            if ((c == mx) && (c > mean)) condMask |= (1u << r);
        }
    }
    int wv = t >> 6, lane = t & 63;
    #pragma unroll
    for (int r = 0; r < 16; r++) {
        u64 m = __ballot((condMask >> r) & 1u);
        if (lane == 0)
            seedB[((size_t)b*H + y0 + r)*WPR + xb*4 + wv] = m;
    }
}

// ------- flood: thread-per-row tiles (256 rows), O(1) horizontal run-fill, guarded passes -------
__global__ __launch_bounds__(256) void floodTileK(const u64* __restrict__ Mb,
        const u64* __restrict__ seedB, u64* __restrict__ Rb,
        unsigned* __restrict__ chg, int t) {
    if (t > 0 && chg[t-1] == 0) return;
    int b = blockIdx.y;
    int y0 = blockIdx.x * 256;
    int ty = threadIdx.x;
    int y = y0 + ty;
    const u64* M = Mb + (size_t)b*H*WPR;
    const u64* S = seedB + (size_t)b*H*WPR;
    u64* R = Rb + (size_t)b*H*WPR;
    u64 m[12], r[12], hT[12], hB[12];
    #pragma unroll
    for (int w = 0; w < 12; w++) {
        m[w] = M[y*WPR + w];
        r[w] = (t == 0) ? (m[w] & S[y*WPR + w]) : R[y*WPR + w];
    }
    bool topRow = (ty == 0), botRow = (ty == 255);
    #pragma unroll
    for (int w = 0; w < 12; w++) { hT[w] = 0ULL; hB[w] = 0ULL; }
    if (topRow && y0 > 0) {
        int hy = y0 - 1;
        #pragma unroll
        for (int w = 0; w < 12; w++)
            hT[w] = (t == 0) ? (M[hy*WPR+w] & S[hy*WPR+w]) : R[hy*WPR+w];
    }
    if (botRow && y0 + 256 < H) {
        int hy = y0 + 256;
        #pragma unroll
        for (int w = 0; w < 12; w++)
            hB[w] = (t == 0) ? (M[hy*WPR+w] & S[hy*WPR+w]) : R[hy*WPR+w];
    }
    __shared__ u64 L[256][12];
    __shared__ unsigned chgArr[4];
    #pragma unroll
    for (int w = 0; w < 12; w++) L[ty][w] = r[w];
    __syncthreads();
    int wvid = ty >> 6, lane = ty & 63;
    bool grew = false;
    while (true) {
        u64 D[12], F[12];
        #pragma unroll
        for (int w = 0; w < 12; w++) {
            u64 up = topRow ? hT[w] : L[ty-1][w];
            u64 dn = botRow ? hB[w] : L[ty+1][w];
            D[w] = r[w] | up | dn;
        }
        #pragma unroll
        for (int w = 0; w < 12; w++) {
            u64 s = D[w] | (D[w] << 1) | (D[w] >> 1);
            if (w > 0)  s |= D[w-1] >> 63;
            if (w < 11) s |= D[w+1] << 63;
            F[w] = s & m[w];
        }
        {
            u64 c = 0;
            #pragma unroll
            for (int w = 0; w < 12; w++) {
                u64 sd = (F[w] | c) & m[w];
                u64 uf = m[w] & ~(m[w] + sd);
                F[w] = uf | sd;
                c = uf >> 63;
            }
        }
        {
            u64 c = 0;
            #pragma unroll
            for (int w = 11; w >= 0; w--) {
                u64 sd = (F[w] | (c << 63)) & m[w];
                u64 bm = __brevll(m[w]);
                u64 df = __brevll(bm & ~(bm + __brevll(sd)));
                F[w] = df | sd;
                c = df & 1ULL;
            }
        }
        bool chgT = false;
        #pragma unroll
        for (int w = 0; w < 12; w++) if (F[w] != r[w]) chgT = true;
        bool wc = __any(chgT);
        if (lane == 0) chgArr[wvid] = wc ? 1u : 0u;
        __syncthreads();
        #pragma unroll
        for (int w = 0; w < 12; w++) { r[w] = F[w]; L[ty][w] = F[w]; }
        unsigned any = chgArr[0] | chgArr[1] | chgArr[2] | chgArr[3];
        __syncthreads();
        if (!any) break;
        grew = true;
    }
    #pragma unroll
    for (int w = 0; w < 12; w++) R[y*WPR + w] = r[w];
    if (grew && ty == 0) atomicOr(&chg[t], 1u);
}

// ---------------- final: out = (sigmoid?(pred)>0.5) | reach ----------------
__global__ void finalK(const float* __restrict__ pred, const u64* __restrict__ reachB,
                       const unsigned* __restrict__ sc, float* __restrict__ out) {
    int b = blockIdx.z, y = blockIdx.y, x = blockIdx.x*256 + threadIdx.x;
    float pmn = fdec(sc[16 + b]), pmx = fdec(sc[24 + b]);
    bool needSig = (pmx > 1.0f) || (pmn < 0.0f);
    float p = pred[((size_t)b*H + y)*W + x];
    float pv;
    if (needSig) {
        float e = (float)exp(-(double)p);
        pv = 1.f / (1.f + e);
    } else {
        pv = p;
    }
    bool on = pv > 0.5f;
    u64 w = reachB[((size_t)b*H + y)*WPR + (x >> 6)];
    on = on || ((w >> (x & 63)) & 1ULL);
    out[((size_t)b*H + y)*W + x] = on ? 1.f : 0.f;
}

extern "C" void kernel_launch(void* const* d_in, const int* in_sizes, int n_in,
                              void* d_out, int out_size, void* d_ws, size_t ws_size,
                              hipStream_t stream) {
    const float* pred = (const float*)d_in[0];
    const float* img  = (const float*)d_in[1];
    float* out = (float*)d_out;
    char* ws = (char*)d_ws;

    float*    wtab   = (float*)(ws + 1024);
    unsigned* sc     = (unsigned*)(ws + 16384);
    float*    fsum   = ((float*)sc) + 32;
    unsigned* chg    = sc + 64;
    float*    p12    = (float*)(ws + 20480);
    u64*      maskB  = (u64*)(ws + 1310720);
    u64*      seedB  = (u64*)(ws + 1900544);
    u64*      reachB = (u64*)(ws + 2490368);
    const size_t PL = (size_t)NB*NP;
    float* plane = (float*)(ws + 4194304);
    float* b0  = plane;          // gauss tmp
    float* b1  = plane + PL;     // enh
    float* h0c = plane + 2*PL; float* h0s = plane + 3*PL;
    float* h1c = plane + 4*PL; float* h3c = plane + 5*PL;
    float* f0  = plane + 8*PL; float* f1 = plane + 9*PL;
    float* f2  = plane + 10*PL; float* f3 = plane + 11*PL;

    const float* gpadH8 = wtab;
    const float* gpadV  = wtab + 128;

    initK<<<1, 256, 0, stream>>>(wtab, sc);
    reduceK<<<dim3(64, 8), 256, 0, stream>>>(img, pred, sc);

    gaussHK3<<<dim3(384, 8), 192, 0, stream>>>(img, b0, gpadH8, sc);
    gaussVK4<<<2304, 128, 0, stream>>>(b0, img, b1, gpadV, sc);

    gaborHS8<<<dim3(384, 8), 192, 0, stream>>>(b1, h0c, h0s, h1c, h3c, wtab, maskB);

    gaborVAB<<<2304, 128, 0, stream>>>(h0c, h0s, f0, f2,
                                       wtab + 768, wtab + 896,
                                       p12, p12 + 2*P12N);
    gaborV13<<<2304, 128, 0, stream>>>(h1c, h3c, f1, f3,
                                       wtab + 1024, wtab + 1408,
                                       p12 + P12N, p12 + 3*P12N);
    sumKAll<<<dim3(8, 4), 256, 0, stream>>>(p12, fsum);

    seedK4<<<1152, 256, 0, stream>>>(f0, f1, f2, f3, fsum, seedB);

    for (int t = 0; t < FLOOD_PASSES; t++)
        floodTileK<<<dim3(3, 8), 256, 0, stream>>>(maskB, seedB, reachB, chg, t);

    finalK<<<dim3(3, H, 8), 256, 0, stream>>>(pred, reachB, sc, out);
}

// Round 15
// 240.734 us; speedup vs baseline: 1.3791x; 1.0125x over previous
//
#include <hip/hip_runtime.h>
#include <math.h>

typedef unsigned long long u64;

#define W 768
#define H 768
#define NP (768*768)
#define NB 8
#define WPR 12              // u64 words per row (768/64)
#define NW (NB*H*WPR)       // total words per bit buffer = 73728
#define TH 16               // output rows per block in tiled vertical convs
#define P12N 73728          // floats per p12 angle region (8*768*12)
#define FLOOD_PASSES 6

#define PADI(q) ((q) + ((q) >> 5))   // LDS pad: +1 word per 32

// ---------- ws layout (bytes) ----------
// 1024    : wtab (floats, 1536 entries):
//           [0..115] gpadH8 (tap j at [7+j], 101 real taps, zero-padded to 116)
//           [128..290] gpadV (tap j at [31+j])
//           [384+p*64]  H tables, d = i-27, real |d|<=r: p:0=h0c 1=h0s 2=h1c 5=h3c
//           [768+q*128] V tables (tap j at [31+j], zero-padded):
//                q: 0=v0c(R12) 1=v0s(R12) 2=v1c(R17) 5=v3c(R17)
// 16384   : sc (u32): [0..7] imgMinEnc [8..15] imgMaxEnc [16..23] predMinEnc
//           [24..31] predMaxEnc [32..63] fsum(f32) [64..127] chg flags
// 20480   : p12[4 angles][73728] f32
// 1310720 : maskBits u64[NW]
// 1900544 : seedBits u64[NW]
// 2490368 : reachBits u64[NW]
// 4 MiB   : planes: 0:b0(tmp) 1:b1(enh) 2:h0c 3:h0s 4:h1c 5:h3c 8:f0 9:f1 10:f2 11:f3

__device__ __forceinline__ unsigned fenc(float f) {
    unsigned b = __float_as_uint(f);
    return b ^ ((unsigned)((int)b >> 31) | 0x80000000u);
}
__device__ __forceinline__ float fdec(unsigned u) {
    unsigned b = (u & 0x80000000u) ? (u ^ 0x80000000u) : ~u;
    return __uint_as_float(b);
}
__device__ __forceinline__ int refl101(int i, int n) {
    if (i < 0) i = -i;
    if (i >= n) i = 2*n - 2 - i;
    return i;
}
__device__ __forceinline__ int symref(int i, int n) {
    if (i < 0) i = -1 - i;
    if (i >= n) i = 2*n - 1 - i;
    return i;
}

// ---------------- init: parallel weight tables + scalar init ----------------
__global__ void initK(float* wtab, unsigned* sc) {
    int t = threadIdx.x;
    __shared__ double gd[101];
    __shared__ double ssumS;
    const double sig = 15.5;
    if (t < 101) { double xx = t - 50; gd[t] = exp(-xx*xx/(2.0*sig*sig)); }
    __syncthreads();
    if (t == 0) {
        double s = 0.0;                       // identical sequential order -> identical ssum
        for (int i = 0; i < 101; i++) s += gd[i];
        ssumS = s;
    }
    __syncthreads();
    double ssum = ssumS;
    for (int i = t; i < 116; i += 256) {      // gpadH8: tap j at [7+j]
        float v = 0.f; int j = i - 7;
        if (j >= 0 && j < 101) v = (float)(gd[j]/ssum);
        wtab[i] = v;
    }
    for (int i = t; i < 163; i += 256) {      // gpadV: tap j at [31+j]
        float v = 0.f; int j = i - 31;
        if (j >= 0 && j < 101) v = (float)(gd[j]/ssum);
        wtab[128 + i] = v;
    }
    const double thetas[4] = {45.0, 90.0, 135.0, 180.0};
    const int    rad[4]    = {12, 17, 12, 17};
    const double sg = ((1.0/M_PI) * sqrt(log(2.0)/2.0) * 3.0) / 0.1;
    const double C  = 1.0/(2.0*M_PI*sg*sg);
    const int hG[6]   = {0, 0, 1, 2, 2, 3};
    const int hSin[6] = {0, 1, 0, 0, 1, 0};
    for (int idx = t; idx < 6*64; idx += 256) {   // H tables: d = i-27
        int p = idx / 64, i = idx % 64;
        int g = hG[p], r = rad[g];
        double th = thetas[g] * (M_PI / 180.0);
        double a  = 2.0*M_PI*0.1*cos(th);
        float v = 0.f;
        int d = i - 27;
        if (d >= -r && d <= r) {
            double dd = (double)d, G = exp(-0.5*dd*dd/(sg*sg));
            v = hSin[p] ? (float)(C*G*sin(a*dd)) : (float)(C*G*cos(a*dd));
        }
        wtab[384 + p*64 + i] = v;
    }
    const int vG[6]   = {0, 0, 1, 2, 2, 3};
    const int vSin[6] = {0, 1, 0, 0, 1, 0};
    for (int idx = t; idx < 6*128; idx += 256) {
        int q = idx / 128, i = idx % 128;
        int g = vG[q], r = rad[g];
        double th = thetas[g] * (M_PI / 180.0);
        double bb = 2.0*M_PI*0.1*sin(th);
        float v = 0.f;
        int j = i - 31;
        if (j >= 0 && j <= 2*r) {
            double dd = (double)(j - r), G = exp(-0.5*dd*dd/(sg*sg));
            v = vSin[q] ? (float)(G*sin(bb*dd)) : (float)(G*cos(bb*dd));
        }
        wtab[768 + q*128 + i] = v;
    }
    if (t < 8)  { sc[t] = 0xFFFFFFFFu; sc[8+t] = 0u; sc[16+t] = 0xFFFFFFFFu; sc[24+t] = 0u; }
    if (t >= 32 && t < 64) ((float*)sc)[t] = 0.f;        // fsum
    if (t >= 64 && t < 128) sc[t] = 0u;                  // chg flags
}

// ---------------- per-image min/max of img and pred ----------------
__global__ void reduceK(const float* __restrict__ img, const float* __restrict__ pred,
                        unsigned* sc) {
    int b = blockIdx.y;
    int base = b*NP + blockIdx.x*9216 + threadIdx.x;
    float imn = INFINITY, imx = -INFINITY, pmn = INFINITY, pmx = -INFINITY;
    for (int k = 0; k < 36; k++) {
        float v = img[base + k*256];  imn = fminf(imn, v); imx = fmaxf(imx, v);
        float p = pred[base + k*256]; pmn = fminf(pmn, p); pmx = fmaxf(pmx, p);
    }
    for (int off = 32; off; off >>= 1) {
        imn = fminf(imn, __shfl_down(imn, off));
        imx = fmaxf(imx, __shfl_down(imx, off));
        pmn = fminf(pmn, __shfl_down(pmn, off));
        pmx = fmaxf(pmx, __shfl_down(pmx, off));
    }
    __shared__ float s[4][4];
    int lane = threadIdx.x & 63, wv = threadIdx.x >> 6;
    if (lane == 0) { s[0][wv] = imn; s[1][wv] = imx; s[2][wv] = pmn; s[3][wv] = pmx; }
    __syncthreads();
    if (threadIdx.x == 0) {
        float a0 = s[0][0], a1 = s[1][0], a2 = s[2][0], a3 = s[3][0];
        for (int w = 1; w < 4; w++) {
            a0 = fminf(a0, s[0][w]); a1 = fmaxf(a1, s[1][w]);
            a2 = fminf(a2, s[2][w]); a3 = fmaxf(a3, s[3][w]);
        }
        atomicMin(&sc[b],      fenc(a0));
        atomicMax(&sc[8 + b],  fenc(a1));
        atomicMin(&sc[16 + b], fenc(a2));
        atomicMax(&sc[24 + b], fenc(a3));
    }
}

// ------- Gaussian blur H: 8 outputs/thread, 2 rows/block, padded LDS -------
__global__ __launch_bounds__(192) void gaussHK3(const float* __restrict__ img,
                                                float* __restrict__ out,
                                                const float* __restrict__ wt,
                                                const unsigned* __restrict__ sc) {
    int b = blockIdx.y, y0 = blockIdx.x*2, t = threadIdx.x;
    float mn = fdec(sc[b]), mx = fdec(sc[8 + b]);
    float den = mx - mn;
    __shared__ float sh[2][896];
    const float* rowA = img + ((size_t)b*H + y0)*W;
    const float* rowB = rowA + W;
    for (int q = t; q < 868; q += 192) {
        int gx = refl101(q - 50, W);
        sh[0][PADI(q)] = (rowA[gx] - mn) / den;
        sh[1][PADI(q)] = (rowB[gx] - mn) / den;
    }
    __syncthreads();
    int rsel = t >= 96 ? 1 : 0;
    int tt = t - 96*rsel;
    int qb = 8*tt;
    const float* S = sh[rsel];
    float a[8];
    #pragma unroll
    for (int i = 0; i < 8; i++) a[i] = 0.f;
    #pragma unroll 4
    for (int p = 0; p < 108; p++) {
        float v = S[PADI(qb + p)];
        #pragma unroll
        for (int sub = 0; sub < 8; sub++)
            a[sub] = __fmaf_rn(wt[p + 7 - sub], v, a[sub]);
    }
    size_t o = ((size_t)b*H + y0 + rsel)*W + qb;
    *(float4*)(out + o)     = make_float4(a[0], a[1], a[2], a[3]);
    *(float4*)(out + o + 4) = make_float4(a[4], a[5], a[6], a[7]);
}

// ---------------- Gaussian blur V: unroll x4, XCD-resident image ----------------
__global__ __launch_bounds__(128) void gaussVK4(const float* __restrict__ tmp,
                                                const float* __restrict__ img,
                                                float* __restrict__ enh,
                                                const float* __restrict__ wt,
                                                const unsigned* __restrict__ sc) {
    int bid = blockIdx.x;
    int b = bid & 7; int r_ = bid >> 3; int tile = r_ % 48; int strip = r_ / 48;
    int y0 = tile*TH, x = strip*128 + threadIdx.x;
    float acc[TH];
    #pragma unroll
    for (int k = 0; k < TH; k++) acc[k] = 0.f;
    const float* T = tmp + (size_t)b*NP;
    for (int base = 0; base < 116; base += 4) {
        int g0 = refl101(y0+base-50, H), g1 = refl101(y0+base-49, H),
            g2 = refl101(y0+base-48, H), g3 = refl101(y0+base-47, H);
        float v0 = T[g0*W+x], v1 = T[g1*W+x], v2 = T[g2*W+x], v3 = T[g3*W+x];
        #pragma unroll
        for (int k = 0; k < TH; k++) {
            float a = acc[k];
            a = __fmaf_rn(wt[base   -k+31], v0, a);
            a = __fmaf_rn(wt[base+1 -k+31], v1, a);
            a = __fmaf_rn(wt[base+2 -k+31], v2, a);
            a = __fmaf_rn(wt[base+3 -k+31], v3, a);
            acc[k] = a;
        }
    }
    float mn = fdec(sc[b]), mx = fdec(sc[8 + b]);
    float den = mx - mn;
    #pragma unroll
    for (int k = 0; k < TH; k++) {
        size_t o = ((size_t)b*H + y0 + k)*W + x;
        float vv = (img[o] - mn) / den;
        float e = vv - acc[k];
        e = fminf(fmaxf(e, 0.f), 1.f);
        enh[o] = e;
    }
}

// ------- fused Gabor H (4 planes, 8 out/thread, 2 rows/block) + Sobel mask -------
__global__ __launch_bounds__(192) void gaborHS8(const float* __restrict__ enh,
        float* __restrict__ h0c, float* __restrict__ h0s,
        float* __restrict__ h1c, float* __restrict__ h3c,
        const float* __restrict__ wt, u64* __restrict__ maskB) {
    int b = blockIdx.y, y0 = blockIdx.x*2, t = threadIdx.x;
    __shared__ float sh[4][840];
    __shared__ u64 words[24];
    const float* base = enh + (size_t)b*NP;
    int ra = (y0 == 0) ? 1 : y0 - 1;          // reflect101 row above pair
    int rb = (y0 + 2 <= H - 1) ? y0 + 2 : H - 2;   // row below pair
    const float* rowm = base + (size_t)ra*W;
    const float* rowA = base + (size_t)y0*W;
    const float* rowB = rowA + W;
    const float* rowp = base + (size_t)rb*W;
    for (int q = t; q < 812; q += 192) {
        int gx = symref(q - 20, W);
        sh[0][PADI(q)] = rowm[gx];
        sh[1][PADI(q)] = rowA[gx];
        sh[2][PADI(q)] = rowB[gx];
        sh[3][PADI(q)] = rowp[gx];
    }
    if (t < 24) words[t] = 0ULL;
    __syncthreads();
    const float* T0c = wt + 384; const float* T0s = wt + 448;
    const float* T1c = wt + 512; const float* T3c = wt + 704;
    int rsel = t >= 96 ? 1 : 0;
    int tt = t - 96*rsel;
    int qb = 8*tt;
    const float* S = sh[1 + rsel];
    float a0c[8], a0s[8], a1c[8], a3c[8];
    #pragma unroll
    for (int i = 0; i < 8; i++) { a0c[i] = 0.f; a0s[i] = 0.f; a1c[i] = 0.f; a3c[i] = 0.f; }
    // real tap window: table idx in [10,44] -> p in [3,44] over sub=0..7
    #pragma unroll 4
    for (int p = 3; p < 45; p++) {
        float v = S[PADI(qb + p)];
        #pragma unroll
        for (int sub = 0; sub < 8; sub++) {
            int idx = p + 7 - sub;
            a0c[sub] = __fmaf_rn(T0c[idx], v, a0c[sub]);
            a0s[sub] = __fmaf_rn(T0s[idx], v, a0s[sub]);
            a1c[sub] = __fmaf_rn(T1c[idx], v, a1c[sub]);
            a3c[sub] = __fmaf_rn(T3c[idx], v, a3c[sub]);
        }
    }
    size_t o = ((size_t)b*H + y0 + rsel)*W + qb;
    *(float4*)(h0c + o)     = make_float4(a0c[0], a0c[1], a0c[2], a0c[3]);
    *(float4*)(h0c + o + 4) = make_float4(a0c[4], a0c[5], a0c[6], a0c[7]);
    *(float4*)(h0s + o)     = make_float4(a0s[0], a0s[1], a0s[2], a0s[3]);
    *(float4*)(h0s + o + 4) = make_float4(a0s[4], a0s[5], a0s[6], a0s[7]);
    *(float4*)(h1c + o)     = make_float4(a1c[0], a1c[1], a1c[2], a1c[3]);
    *(float4*)(h1c + o + 4) = make_float4(a1c[4], a1c[5], a1c[6], a1c[7]);
    *(float4*)(h3c + o)     = make_float4(a3c[0], a3c[1], a3c[2], a3c[3]);
    *(float4*)(h3c + o + 4) = make_float4(a3c[4], a3c[5], a3c[6], a3c[7]);

    // ---- Sobel for this thread's 8 pixels (row y0+rsel), reflect101 ----
    const float* Rm = sh[rsel == 0 ? 0 : 1];
    const float* Rc = sh[1 + rsel];
    const float* Rp = (rsel == 0) ? sh[2] : ((y0 == H - 2) ? sh[1] : sh[3]);
    unsigned byte = 0;
    #pragma unroll
    for (int sub = 0; sub < 8; sub++) {
        int c = qb + sub;
        int cm = (c > 0) ? c - 1 : 1;
        int cp = (c < W - 1) ? c + 1 : W - 2;
        int im = PADI(cm + 20), ic = PADI(c + 20), ip = PADI(cp + 20);
        float a00 = Rm[im], a01 = Rm[ic], a02 = Rm[ip];
        float a10 = Rc[im],               a12 = Rc[ip];
        float a20 = Rp[im], a21 = Rp[ic], a22 = Rp[ip];
        float gx = __fmaf_rn(-1.f, a00, 0.f);
        gx = __fmaf_rn( 1.f, a02, gx);
        gx = __fmaf_rn(-2.f, a10, gx);
        gx = __fmaf_rn( 2.f, a12, gx);
        gx = __fmaf_rn(-1.f, a20, gx);
        gx = __fmaf_rn( 1.f, a22, gx);
        float gy = __fmaf_rn(-1.f, a00, 0.f);
        gy = __fmaf_rn(-2.f, a01, gy);
        gy = __fmaf_rn(-1.f, a02, gy);
        gy = __fmaf_rn( 1.f, a20, gy);
        gy = __fmaf_rn( 2.f, a21, gy);
        gy = __fmaf_rn( 1.f, a22, gy);
        float s2 = __fadd_rn(__fmul_rn(gx, gx), __fmul_rn(gy, gy));
        float grad = (float)sqrt((double)s2);
        const float THR = (float)(0.0789 + 1.0*0.0774);
        if (grad >= THR) byte |= 1u << sub;
    }
    atomicOr(&words[rsel*12 + (qb >> 6)], (u64)byte << (qb & 63));
    __syncthreads();
    if (t < 24) {
        int row = y0 + (t / 12);
        maskB[((size_t)b*H + row)*WPR + (t % 12)] = words[t];
    }
}

// ------- Gabor V, 45/135 pair: A=Vc*hc, B=Vs*hs -> f0=A-B, f2=A+B -------
// R12 real window: row offsets bb in [5,44] only (others multiply exact zeros)
__global__ __launch_bounds__(128) void gaborVAB(
        const float* __restrict__ hc, const float* __restrict__ hs,
        float* __restrict__ f0, float* __restrict__ f2,
        const float* __restrict__ Tc, const float* __restrict__ Ts,
        float* __restrict__ p0, float* __restrict__ p2) {
    int bid = blockIdx.x;
    int b = bid & 7; int r_ = bid >> 3; int tile = r_ % 48; int strip = r_ / 48;
    int y0 = tile*TH, x = strip*128 + threadIdx.x;
    float A[TH], Bm[TH];
    #pragma unroll
    for (int k = 0; k < TH; k++) { A[k] = 0.f; Bm[k] = 0.f; }
    const size_t pb = (size_t)b*NP;
    for (int bb = 5; bb < 45; bb += 4) {
        int g0 = symref(y0 + bb - 17, H), g1 = symref(y0 + bb - 16, H);
        int g2 = symref(y0 + bb - 15, H), g3 = symref(y0 + bb - 14, H);
        size_t o0 = pb + (size_t)g0*W + x, o1 = pb + (size_t)g1*W + x;
        size_t o2 = pb + (size_t)g2*W + x, o3 = pb + (size_t)g3*W + x;
        float vc0 = hc[o0], vc1 = hc[o1], vc2 = hc[o2], vc3 = hc[o3];
        float vs0 = hs[o0], vs1 = hs[o1], vs2 = hs[o2], vs3 = hs[o3];
        #pragma unroll
        for (int k = 0; k < TH; k++) {
            int i26 = bb - k + 26;
            float t = A[k];
            t = __fmaf_rn(Tc[i26],   vc0, t);
            t = __fmaf_rn(Tc[i26+1], vc1, t);
            t = __fmaf_rn(Tc[i26+2], vc2, t);
            t = __fmaf_rn(Tc[i26+3], vc3, t);
            A[k] = t;
            t = Bm[k];
            t = __fmaf_rn(Ts[i26],   vs0, t);
            t = __fmaf_rn(Ts[i26+1], vs1, t);
            t = __fmaf_rn(Ts[i26+2], vs2, t);
            t = __fmaf_rn(Ts[i26+3], vs3, t);
            Bm[k] = t;
        }
    }
    int g64 = strip*2 + (threadIdx.x >> 6);
    bool l0 = (threadIdx.x & 63) == 0;
    #pragma unroll
    for (int k = 0; k < TH; k++) {
        size_t o = ((size_t)b*H + y0 + k)*W + x;
        size_t po = ((size_t)b*H + y0 + k)*12 + g64;
        float v0 = A[k] - Bm[k];
        float v2 = A[k] + Bm[k];
        f0[o] = v0;
        float s = v0;
        for (int off = 32; off; off >>= 1) s += __shfl_down(s, off);
        if (l0) p0[po] = s;
        f2[o] = v2;
        s = v2;
        for (int off = 32; off; off >>= 1) s += __shfl_down(s, off);
        if (l0) p2[po] = s;
    }
}

// ------- Gabor V, 90/180 pair: two independent 1-plane chains (unroll x4) -------
__global__ __launch_bounds__(128) void gaborV13(
        const float* __restrict__ h1, const float* __restrict__ h3,
        float* __restrict__ f1, float* __restrict__ f3,
        const float* __restrict__ T1, const float* __restrict__ T3,
        float* __restrict__ p1, float* __restrict__ p3) {
    int bid = blockIdx.x;
    int b = bid & 7; int r_ = bid >> 3; int tile = r_ % 48; int strip = r_ / 48;
    int y0 = tile*TH, x = strip*128 + threadIdx.x;
    float a1[TH], a3[TH];
    #pragma unroll
    for (int k = 0; k < TH; k++) { a1[k] = 0.f; a3[k] = 0.f; }
    const size_t pb = (size_t)b*NP;
    for (int base = 0; base < 48; base += 4) {
        int g0 = symref(y0 + base - 17, H), g1 = symref(y0 + base - 16, H);
        int g2 = symref(y0 + base - 15, H), g3 = symref(y0 + base - 14, H);
        size_t o0 = pb + (size_t)g0*W + x, o1 = pb + (size_t)g1*W + x;
        size_t o2 = pb + (size_t)g2*W + x, o3 = pb + (size_t)g3*W + x;
        float v10 = h1[o0], v11 = h1[o1], v12 = h1[o2], v13 = h1[o3];
        float v30 = h3[o0], v31 = h3[o1], v32 = h3[o2], v33 = h3[o3];
        #pragma unroll
        for (int k = 0; k < TH; k++) {
            int i31 = base - k + 31;
            float t = a1[k];
            t = __fmaf_rn(T1[i31],   v10, t);
            t = __fmaf_rn(T1[i31+1], v11, t);
            t = __fmaf_rn(T1[i31+2], v12, t);
            t = __fmaf_rn(T1[i31+3], v13, t);
            a1[k] = t;
            t = a3[k];
            t = __fmaf_rn(T3[i31],   v30, t);
            t = __fmaf_rn(T3[i31+1], v31, t);
            t = __fmaf_rn(T3[i31+2], v32, t);
            t = __fmaf_rn(T3[i31+3], v33, t);
            a3[k] = t;
        }
    }
    {   // remainder rows: base = 48, 49
        int g0 = symref(y0 + 31, H), g1 = symref(y0 + 32, H);
        size_t o0 = pb + (size_t)g0*W + x, o1 = pb + (size_t)g1*W + x;
        float v10 = h1[o0], v11 = h1[o1];
        float v30 = h3[o0], v31 = h3[o1];
        #pragma unroll
        for (int k = 0; k < TH; k++) {
            int i31 = 48 - k + 31;
            float t = a1[k];
            t = __fmaf_rn(T1[i31],   v10, t);
            t = __fmaf_rn(T1[i31+1], v11, t);
            a1[k] = t;
            t = a3[k];
            t = __fmaf_rn(T3[i31],   v30, t);
            t = __fmaf_rn(T3[i31+1], v31, t);
            a3[k] = t;
        }
    }
    int g64 = strip*2 + (threadIdx.x >> 6);
    bool l0 = (threadIdx.x & 63) == 0;
    #pragma unroll
    for (int k = 0; k < TH; k++) {
        size_t o = ((size_t)b*H + y0 + k)*W + x;
        size_t po = ((size_t)b*H + y0 + k)*12 + g64;
        f1[o] = a1[k];
        float s = a1[k];
        for (int off = 32; off; off >>= 1) s += __shfl_down(s, off);
        if (l0) p1[po] = s;
        f3[o] = a3[k];
        s = a3[k];
        for (int off = 32; off; off >>= 1) s += __shfl_down(s, off);
        if (l0) p3[po] = s;
    }
}

// ---------------- deterministic per-image sums, all 4 angles ----------------
__global__ void sumKAll(const float* __restrict__ p12, float* fsum) {
    int b = blockIdx.x, g = blockIdx.y, t = threadIdx.x;
    const float* P = p12 + (size_t)g*P12N;
    float s = 0.f;
    for (int k = 0; k < 9; k++) {
        int idx = t + k*256;                 // 0..2303 == row*3 + strip
        int row = idx / 3, strip = idx - row*3;
        const float* Q = P + ((size_t)b*H + row)*12 + strip*4;
        float p4 = ((Q[0] + Q[1]) + Q[2]) + Q[3];
        s += p4;
    }
    __shared__ float sm[256];
    sm[t] = s; __syncthreads();
    for (int off = 128; off; off >>= 1) {
        if (t < off) sm[t] += sm[t + off];
        __syncthreads();
    }
    if (t == 0) fsum[g*8 + b] = sm[0];
}

// ---------------- seeds: row-tiled, 4 planes sequential in LDS (XCD swizzle) ----------------
__global__ __launch_bounds__(256) void seedK4(const float* __restrict__ f0,
        const float* __restrict__ f1, const float* __restrict__ f2,
        const float* __restrict__ f3, const float* __restrict__ fsum,
        u64* __restrict__ seedB) {
    int bid = blockIdx.x;
    int b = bid & 7; int r_ = bid >> 3;          // 0..143
    int y0 = (r_ % 48)*16; int xb = r_ / 48;     // 0..2
    int x0 = xb*256, t = threadIdx.x;
    __shared__ float sh[18][258];
    const float* planes[4] = {f0, f1, f2, f3};
    unsigned condMask = 0;
    #pragma unroll
    for (int a = 0; a < 4; a++) {
        const float* F = planes[a] + (size_t)b*NP;
        __syncthreads();
        for (int idx = t; idx < 18*258; idx += 256) {
            int rr = idx / 258, q = idx - rr*258;
            int gy = y0 - 1 + rr; gy = gy < 0 ? 0 : (gy > H-1 ? H-1 : gy);
            int gx = x0 - 1 + q;  gx = gx < 0 ? 0 : (gx > W-1 ? W-1 : gx);
            sh[rr][q] = F[gy*W + gx];
        }
        __syncthreads();
        float mean = fsum[a*8 + b] / 589824.f;
        #pragma unroll
        for (int r = 0; r < 16; r++) {
            float c = sh[r+1][t+1];
            float mx = c;
            mx = fmaxf(mx, sh[r  ][t]); mx = fmaxf(mx, sh[r  ][t+1]); mx = fmaxf(mx, sh[r  ][t+2]);
            mx = fmaxf(mx, sh[r+1][t]); mx = fmaxf(mx, sh[r+1][t+1]); mx = fmaxf(mx, sh[r+1][t+2]);
            mx = fmaxf(mx, sh[r+2][t]); mx = fmaxf(mx, sh[r+2][t+1]); mx = fmaxf(mx, sh[r+2][t+2]);
            if ((c == mx) && (c > mean)) condMask |= (1u << r);
        }
    }
    int wv = t >> 6, lane = t & 63;
    #pragma unroll
    for (int r = 0; r < 16; r++) {
        u64 m = __ballot((condMask >> r) & 1u);
        if (lane == 0)
            seedB[((size_t)b*H + y0 + r)*WPR + xb*4 + wv] = m;
    }
}

// ------- flood: thread-per-row tiles (256 rows), O(1) horizontal run-fill, guarded passes -------
__global__ __launch_bounds__(256) void floodTileK(const u64* __restrict__ Mb,
        const u64* __restrict__ seedB, u64* __restrict__ Rb,
        unsigned* __restrict__ chg, int t) {
    if (t > 0 && chg[t-1] == 0) return;
    int b = blockIdx.y;
    int y0 = blockIdx.x * 256;
    int ty = threadIdx.x;
    int y = y0 + ty;
    const u64* M = Mb + (size_t)b*H*WPR;
    const u64* S = seedB + (size_t)b*H*WPR;
    u64* R = Rb + (size_t)b*H*WPR;
    u64 m[12], r[12], hT[12], hB[12];
    #pragma unroll
    for (int w = 0; w < 12; w++) {
        m[w] = M[y*WPR + w];
        r[w] = (t == 0) ? (m[w] & S[y*WPR + w]) : R[y*WPR + w];
    }
    bool topRow = (ty == 0), botRow = (ty == 255);
    #pragma unroll
    for (int w = 0; w < 12; w++) { hT[w] = 0ULL; hB[w] = 0ULL; }
    if (topRow && y0 > 0) {
        int hy = y0 - 1;
        #pragma unroll
        for (int w = 0; w < 12; w++)
            hT[w] = (t == 0) ? (M[hy*WPR+w] & S[hy*WPR+w]) : R[hy*WPR+w];
    }
    if (botRow && y0 + 256 < H) {
        int hy = y0 + 256;
        #pragma unroll
        for (int w = 0; w < 12; w++)
            hB[w] = (t == 0) ? (M[hy*WPR+w] & S[hy*WPR+w]) : R[hy*WPR+w];
    }
    __shared__ u64 L[256][12];
    __shared__ unsigned chgArr[4];
    #pragma unroll
    for (int w = 0; w < 12; w++) L[ty][w] = r[w];
    __syncthreads();
    int wvid = ty >> 6, lane = ty & 63;
    bool grew = false;
    while (true) {
        u64 D[12], F[12];
        #pragma unroll
        for (int w = 0; w < 12; w++) {
            u64 up = topRow ? hT[w] : L[ty-1][w];
            u64 dn = botRow ? hB[w] : L[ty+1][w];
            D[w] = r[w] | up | dn;
        }
        #pragma unroll
        for (int w = 0; w < 12; w++) {
            u64 s = D[w] | (D[w] << 1) | (D[w] >> 1);
            if (w > 0)  s |= D[w-1] >> 63;
            if (w < 11) s |= D[w+1] << 63;
            F[w] = s & m[w];
        }
        {
            u64 c = 0;
            #pragma unroll
            for (int w = 0; w < 12; w++) {
                u64 sd = (F[w] | c) & m[w];
                u64 uf = m[w] & ~(m[w] + sd);
                F[w] = uf | sd;
                c = uf >> 63;
            }
        }
        {
            u64 c = 0;
            #pragma unroll
            for (int w = 11; w >= 0; w--) {
                u64 sd = (F[w] | (c << 63)) & m[w];
                u64 bm = __brevll(m[w]);
                u64 df = __brevll(bm & ~(bm + __brevll(sd)));
                F[w] = df | sd;
                c = df & 1ULL;
            }
        }
        bool chgT = false;
        #pragma unroll
        for (int w = 0; w < 12; w++) if (F[w] != r[w]) chgT = true;
        bool wc = __any(chgT);
        if (lane == 0) chgArr[wvid] = wc ? 1u : 0u;
        __syncthreads();
        #pragma unroll
        for (int w = 0; w < 12; w++) { r[w] = F[w]; L[ty][w] = F[w]; }
        unsigned any = chgArr[0] | chgArr[1] | chgArr[2] | chgArr[3];
        __syncthreads();
        if (!any) break;
        grew = true;
    }
    #pragma unroll
    for (int w = 0; w < 12; w++) R[y*WPR + w] = r[w];
    if (grew && ty == 0) atomicOr(&chg[t], 1u);
}

// ---------------- final: out = (sigmoid?(pred)>0.5) | reach ----------------
__global__ void finalK(const float* __restrict__ pred, const u64* __restrict__ reachB,
                       const unsigned* __restrict__ sc, float* __restrict__ out) {
    int b = blockIdx.z, y = blockIdx.y, x = blockIdx.x*256 + threadIdx.x;
    float pmn = fdec(sc[16 + b]), pmx = fdec(sc[24 + b]);
    bool needSig = (pmx > 1.0f) || (pmn < 0.0f);
    float p = pred[((size_t)b*H + y)*W + x];
    float pv;
    if (needSig) {
        float e = (float)exp(-(double)p);
        pv = 1.f / (1.f + e);
    } else {
        pv = p;
    }
    bool on = pv > 0.5f;
    u64 w = reachB[((size_t)b*H + y)*WPR + (x >> 6)];
    on = on || ((w >> (x & 63)) & 1ULL);
    out[((size_t)b*H + y)*W + x] = on ? 1.f : 0.f;
}

extern "C" void kernel_launch(void* const* d_in, const int* in_sizes, int n_in,
                              void* d_out, int out_size, void* d_ws, size_t ws_size,
                              hipStream_t stream) {
    const float* pred = (const float*)d_in[0];
    const float* img  = (const float*)d_in[1];
    float* out = (float*)d_out;
    char* ws = (char*)d_ws;

    float*    wtab   = (float*)(ws + 1024);
    unsigned* sc     = (unsigned*)(ws + 16384);
    float*    fsum   = ((float*)sc) + 32;
    unsigned* chg    = sc + 64;
    float*    p12    = (float*)(ws + 20480);
    u64*      maskB  = (u64*)(ws + 1310720);
    u64*      seedB  = (u64*)(ws + 1900544);
    u64*      reachB = (u64*)(ws + 2490368);
    const size_t PL = (size_t)NB*NP;
    float* plane = (float*)(ws + 4194304);
    float* b0  = plane;          // gauss tmp
    float* b1  = plane + PL;     // enh
    float* h0c = plane + 2*PL; float* h0s = plane + 3*PL;
    float* h1c = plane + 4*PL; float* h3c = plane + 5*PL;
    float* f0  = plane + 8*PL; float* f1 = plane + 9*PL;
    float* f2  = plane + 10*PL; float* f3 = plane + 11*PL;

    const float* gpadH8 = wtab;
    const float* gpadV  = wtab + 128;

    initK<<<1, 256, 0, stream>>>(wtab, sc);
    reduceK<<<dim3(64, 8), 256, 0, stream>>>(img, pred, sc);

    gaussHK3<<<dim3(384, 8), 192, 0, stream>>>(img, b0, gpadH8, sc);
    gaussVK4<<<2304, 128, 0, stream>>>(b0, img, b1, gpadV, sc);

    gaborHS8<<<dim3(384, 8), 192, 0, stream>>>(b1, h0c, h0s, h1c, h3c, wtab, maskB);

    gaborVAB<<<2304, 128, 0, stream>>>(h0c, h0s, f0, f2,
                                       wtab + 768, wtab + 896,
                                       p12, p12 + 2*P12N);
    gaborV13<<<2304, 128, 0, stream>>>(h1c, h3c, f1, f3,
                                       wtab + 1024, wtab + 1408,
                                       p12 + P12N, p12 + 3*P12N);
    sumKAll<<<dim3(8, 4), 256, 0, stream>>>(p12, fsum);

    seedK4<<<1152, 256, 0, stream>>>(f0, f1, f2, f3, fsum, seedB);

    for (int t = 0; t < FLOOD_PASSES; t++)
        floodTileK<<<dim3(3, 8), 256, 0, stream>>>(maskB, seedB, reachB, chg, t);

    finalK<<<dim3(3, H, 8), 256, 0, stream>>>(pred, reachB, sc, out);
}